// Round 8
// baseline (544.680 us; speedup 1.0000x reference)
//
#include <hip/hip_runtime.h>
#include <hip/hip_cooperative_groups.h>
#include <math.h>

namespace cg = cooperative_groups;

#define DPI 3.141592653589793238462643383279502884

// ---------------- device helpers ----------------
__device__ __forceinline__ float wave_sum64(float v) {
#pragma unroll
  for (int off = 32; off > 0; off >>= 1) v += __shfl_xor(v, off, 64);
  return v;
}

__device__ __forceinline__ float gelu_tanh(float v) {
  float u = 0.7978845608028654f * (v + 0.044715f * v * v * v);
  return 0.5f * v * (1.0f + tanhf(u));
}

// ======================= fused cooperative kernel =======================
struct AllArgs {
  const float *x, *temb, *scw, *scb, *swr, *swi, *strw, *strb, *stiw, *stib;
  const float *c1w, *c1b, *stw, *stb, *sweight, *c2w, *c2b, *lns, *lnb;
  float* out;
  float* A2;  // float2[64*64*64]
  float* Mm;
  float* bias2;
  float* tv;  // [128]
  float* Deff;
  float* Dinv;
  float *ftmA_re, *ftmA_im, *ftmB_re, *ftmB_im;
  float *flmA_re, *flmA_im, *flmB_re, *flmB_im;
  // aliases (stage-disjoint lifetimes)
  float *s_re, *s_im, *h_re, *h_im;
  float *fos_re, *fos_im, *foh_re, *foh_im;
  float *xsbA, *xsbB, *hsbA, *hsbB;
};

#define CN255F ((float)(-2.0 * DPI / 255.0))
#define CN127F ((float)(2.0 * DPI / 127.0))

__device__ __forceinline__ void wigner_block(int b, int tid, const AllArgs& a, char* sm) {
  double* red = (double*)sm;          // [64]
  float* clf = (float*)(sm + 512);    // [64]
  int mode = (b < 128) ? 0 : 1;
  if (tid < 64) clf[tid] = (float)(-sqrt((2.0 * tid + 1.0) / (4.0 * DPI)));
  int t, mm;
  if (mode == 0) { t = b; mm = tid; }
  else { mm = b - 128; t = tid; }
  double denomN = (mode == 0) ? 255.0 : 127.0;
  double beta = (2.0 * t + 1.0) * DPI / denomN;
  float coeff = 1.0f;
  if (mode == 0) {
    if (tid < 63) {
      int k = 2 * (tid + 1);
      red[tid] = 8.0 * cos((double)k * beta) / (1.0 - (double)k * (double)k);
    } else if (tid == 63) {
      red[63] = 4.0;
    }
    __syncthreads();
    for (int s = 32; s > 0; s >>= 1) {
      if (tid < s) red[tid] += red[tid + s];
      __syncthreads();
    }
    double s = red[0] / 255.0;
    if (t == 127) s *= 0.5;
    coeff = (float)(s * (2.0 * DPI / 255.0));
  } else {
    __syncthreads();
  }
  bool active = (mode == 0) ? (tid < 127) : (tid < 64);
  if (!active) return;  // no more barriers below (block-local ok: guarded threads idle)
  int m = mm - 63;
  double cb = cos(beta);
  double ch = cos(0.5 * beta), sh = sin(0.5 * beta);
  int am = (m < 0) ? -m : m;
  int l0v = (am > 1) ? am : 1;
  double seed;
  if (m >= 1) {
    double j = (double)m;
    double K = exp(0.5 * (lgamma(2.0 * j + 1.0) - lgamma(j) - lgamma(j + 2.0)));
    double sgn = ((m + 1) & 1) ? -1.0 : 1.0;
    seed = sgn * K * pow(ch, j - 1.0) * pow(sh, j + 1.0);
  } else if (m <= -1) {
    double j = (double)(-m);
    double K = exp(0.5 * (lgamma(2.0 * j + 1.0) - lgamma(j) - lgamma(j + 2.0)));
    seed = K * pow(ch, j + 1.0) * pow(sh, j - 1.0);
  } else {
    seed = -sqrt(2.0) * sh * ch;
  }
  float dl = (float)seed, dm1 = 0.0f, S_cur = 0.0f;
  float cbf = (float)cb, mf = (float)m;
  for (int l = 0; l < 64; ++l) {
    float val = 0.0f;
    if (l >= l0v) {
      val = dl * coeff * clf[l];
      float Ld = (float)l, lp = Ld + 1.0f;
      float S_next = sqrtf((lp * lp - mf * mf) * (lp * lp - 1.0f));
      float num1 = (2.0f * Ld + 1.0f) * (Ld * lp * cbf + mf);
      float dn = (num1 * dl - lp * S_cur * dm1) / (Ld * S_next);
      dm1 = dl; dl = dn; S_cur = S_next;
    }
    if (mode == 0) a.Deff[((size_t)t * 127 + mm) * 64 + l] = val;
    else a.Dinv[((size_t)mm * 64 + l) * 64 + t] = val;
  }
}

__device__ __forceinline__ void a2_block(int l, int tid, const AllArgs& a, char* sm) {
  float* redr = (float*)sm;            // [256]
  float* redi = (float*)(sm + 1024);   // [256]
  redr[tid] = a.temb[tid] * a.strw[tid * 64 + l];
  redi[tid] = a.temb[tid] * a.stiw[tid * 64 + l];
  __syncthreads();
  for (int s = 128; s > 0; s >>= 1) {
    if (tid < s) { redr[tid] += redr[tid + s]; redi[tid] += redi[tid + s]; }
    __syncthreads();
  }
  float tr = redr[0] + a.strb[l], ti = redi[0] + a.stib[l];
  int o = tid & 63, iq = tid >> 6;
  float2* A2 = (float2*)a.A2;
  for (int i = iq * 16; i < iq * 16 + 16; ++i) {
    int idx = (l * 64 + i) * 64 + o;
    float r = a.swr[idx], s2 = a.swi[idx];
    A2[idx] = make_float2(a.scw[i * 64 + o] + tr * r - ti * s2, tr * s2 + ti * r);
  }
}

__device__ __forceinline__ void m_block(int j, int tid, const AllArgs& a, char* sm) {
  float* buf = (float*)sm;             // [256]
  float* tvsh = (float*)(sm + 1024);   // [64]
  int o = tid & 63, part = tid >> 6;
  float p = 0.f;
  for (int k = part * 64; k < part * 64 + 64; ++k) p = fmaf(a.temb[k], a.stw[k * 128 + o], p);
  buf[part * 64 + o] = p;
  __syncthreads();
  if (part == 0) tvsh[o] = buf[o] + buf[64 + o] + buf[128 + o] + buf[192 + o] + a.stb[o];
  __syncthreads();
  float tvo = tvsh[o];
  float q = 0.f;
  for (int i = part * 16; i < part * 16 + 16; ++i)
    q = fmaf(a.c1w[j * 64 + i], a.sweight[i * 64 + o], q);
  __syncthreads();
  buf[part * 64 + o] = q;
  __syncthreads();
  if (part == 0) a.Mm[j * 64 + o] = tvo * (buf[o] + buf[64 + o] + buf[128 + o] + buf[192 + o]);
  if (j == 0) {
    float bq = 0.f;
    for (int i = part * 16; i < part * 16 + 16; ++i)
      bq = fmaf(a.c1b[i], a.sweight[i * 64 + o], bq);
    __syncthreads();
    buf[part * 64 + o] = bq;
    __syncthreads();
    if (part == 0) a.bias2[o] = tvo * (buf[o] + buf[64 + o] + buf[128 + o] + buf[192 + o]);
  }
}

__device__ __forceinline__ void tv_block(int tid, const AllArgs& a, char* sm) {
  float* buf = (float*)sm;  // [256]
  int o = tid & 127, part = tid >> 7;
  float p = 0.f;
  for (int k = part * 128; k < part * 128 + 128; ++k)
    p = fmaf(a.temb[k], a.stw[k * 128 + o], p);
  buf[part * 128 + o] = p;
  __syncthreads();
  if (part == 0) a.tv[o] = buf[o] + buf[128 + o] + a.stb[o];
}

__device__ __forceinline__ void dft_block(int idx, int tid, const AllArgs& a, char* sm) {
  float* xs_ = (float*)sm;             // [64][64]
  float* tsr = (float*)(sm + 16384);   // [64][64]
  float* tsi = (float*)(sm + 32768);   // [64][64]
  int t = idx >> 2, mh = (idx >> 1) & 1, ph = idx & 1;
  float* ore = ph ? a.ftmB_re : a.ftmA_re;
  float* oim = ph ? a.ftmB_im : a.ftmA_im;
  int pbase = ph * 128;
  int Ktot = ph ? 127 : 128;
  int cg_ = tid & 15, mg = tid >> 4;
  float accr[4][4], acci[4][4];
#pragma unroll
  for (int j = 0; j < 4; ++j)
#pragma unroll
    for (int q = 0; q < 4; ++q) { accr[j][q] = 0.f; acci[j][q] = 0.f; }
  for (int k0 = 0; k0 < Ktot; k0 += 64) {
    int kn = (Ktot - k0 < 64) ? Ktot - k0 : 64;
    __syncthreads();
    {
      int r = tid >> 2, c4 = (tid & 3) * 16;
      if (r < kn) {
        const float4* src = (const float4*)(a.x + ((size_t)t * 255 + pbase + k0 + r) * 64 + c4);
        float4* dst = (float4*)&xs_[r * 64 + c4];
        dst[0] = src[0]; dst[1] = src[1]; dst[2] = src[2]; dst[3] = src[3];
      }
    }
    for (int e = tid; e < 64 * 64; e += 256) {
      int r = e >> 6, mi = e & 63;
      if (r < kn) {
        int gcol = mh * 64 + mi; if (gcol > 126) gcol = 126;
        int p = pbase + k0 + r;
        float ang = CN255F * (float)((gcol - 63) * p);
        float sv, cv;
        __sincosf(ang, &sv, &cv);
        tsr[r * 64 + mi] = cv; tsi[r * 64 + mi] = sv;
      }
    }
    __syncthreads();
#pragma unroll 4
    for (int k = 0; k < kn; ++k) {
      float4 xv = *(const float4*)&xs_[k * 64 + cg_ * 4];
      float4 tr4 = *(const float4*)&tsr[k * 64 + mg * 4];
      float4 ti4 = *(const float4*)&tsi[k * 64 + mg * 4];
      float xv4[4] = {xv.x, xv.y, xv.z, xv.w};
      float trv[4] = {tr4.x, tr4.y, tr4.z, tr4.w};
      float tiv[4] = {ti4.x, ti4.y, ti4.z, ti4.w};
#pragma unroll
      for (int j = 0; j < 4; ++j)
#pragma unroll
        for (int q = 0; q < 4; ++q) {
          accr[j][q] = fmaf(xv4[q], trv[j], accr[j][q]);
          acci[j][q] = fmaf(xv4[q], tiv[j], acci[j][q]);
        }
    }
  }
  __syncthreads();
#pragma unroll
  for (int j = 0; j < 4; ++j) {
    int gmm = mh * 64 + mg * 4 + j;
    if (gmm > 126) continue;
    size_t ob = ((size_t)t * 127 + gmm) * 64 + cg_ * 4;
    *(float4*)(ore + ob) = make_float4(accr[j][0], accr[j][1], accr[j][2], accr[j][3]);
    *(float4*)(oim + ob) = make_float4(acci[j][0], acci[j][1], acci[j][2], acci[j][3]);
  }
}

__device__ __forceinline__ void projf_block(int idx, int tid, const AllArgs& a, char* sm) {
  float* Dsh = (float*)sm;            // [64][32]
  float* fr_ = (float*)(sm + 8192);   // [64][64]
  float* fi_ = (float*)(sm + 24576);  // [64][64]
  int mm = idx >> 2, lh = (idx >> 1) & 1, th = idx & 1;
  float* ore = th ? a.flmB_re : a.flmA_re;
  float* oim = th ? a.flmB_im : a.flmA_im;
  int tb = th * 64;
  int cg_ = tid & 15, lg = tid >> 4;
  for (int e = tid; e < 64 * 32; e += 256) {
    int r = e >> 5, li = e & 31;
    Dsh[r * 32 + li] = a.Deff[((size_t)(tb + r) * 127 + mm) * 64 + lh * 32 + li];
  }
  for (int e = tid; e < 64 * 64; e += 256) {
    int r = e >> 6, c = e & 63;
    size_t idx2 = ((size_t)(tb + r) * 127 + mm) * 64 + c;
    fr_[r * 64 + c] = a.ftmA_re[idx2] + a.ftmB_re[idx2];
    fi_[r * 64 + c] = a.ftmA_im[idx2] + a.ftmB_im[idx2];
  }
  __syncthreads();
  float ar[2][4], ai[2][4];
#pragma unroll
  for (int li = 0; li < 2; ++li)
#pragma unroll
    for (int q = 0; q < 4; ++q) { ar[li][q] = 0.f; ai[li][q] = 0.f; }
#pragma unroll 4
  for (int k = 0; k < 64; ++k) {
    float4 fr4 = *(const float4*)&fr_[k * 64 + cg_ * 4];
    float4 fi4 = *(const float4*)&fi_[k * 64 + cg_ * 4];
    float2 d2 = *(const float2*)&Dsh[k * 32 + lg * 2];
    float frv[4] = {fr4.x, fr4.y, fr4.z, fr4.w};
    float fiv[4] = {fi4.x, fi4.y, fi4.z, fi4.w};
    float dv[2] = {d2.x, d2.y};
#pragma unroll
    for (int li = 0; li < 2; ++li)
#pragma unroll
      for (int q = 0; q < 4; ++q) {
        ar[li][q] = fmaf(dv[li], frv[q], ar[li][q]);
        ai[li][q] = fmaf(dv[li], fiv[q], ai[li][q]);
      }
  }
  __syncthreads();
#pragma unroll
  for (int li = 0; li < 2; ++li) {
    size_t row = ((size_t)mm * 64 + lh * 32 + lg * 2 + li) * 64 + cg_ * 4;
    *(float4*)(ore + row) = make_float4(ar[li][0], ar[li][1], ar[li][2], ar[li][3]);
    *(float4*)(oim + row) = make_float4(ai[li][0], ai[li][1], ai[li][2], ai[li][3]);
  }
}

__device__ __forceinline__ void mix_block(int idx, int tid, const AllArgs& a, char* sm) {
  float* Ar_ = (float*)sm;             // [64][32]
  float* Ai_ = (float*)(sm + 8192);
  float* Msh = (float*)(sm + 16384);
  float* Br_ = (float*)(sm + 24576);   // [64][65]
  float* Bi_ = (float*)(sm + 41216);
  int l = idx >> 2, mh = (idx >> 1) & 1, oh = idx & 1;
  // Sl[l] = sum_t Deff[t][63][l] (needed only for mh==0)
  float slv;
  {
    float* rb = (float*)sm;
    rb[tid] = (mh == 0 && tid < 128) ? a.Deff[((size_t)tid * 127 + 63) * 64 + l] : 0.f;
    __syncthreads();
    for (int s = 128; s > 0; s >>= 1) {
      if (tid < s) rb[tid] += rb[tid + s];
      __syncthreads();
    }
    slv = rb[0];
    __syncthreads();
  }
  int og = tid & 15, mg = tid >> 4;
  for (int e = tid; e < 64 * 32; e += 256) {
    int r = e >> 5, oi = e & 31;
    float2 av = ((const float2*)a.A2)[((size_t)l * 64 + r) * 64 + oh * 32 + oi];
    Ar_[r * 32 + oi] = av.x; Ai_[r * 32 + oi] = av.y;
    Msh[r * 32 + oi] = a.Mm[r * 64 + oh * 32 + oi];
  }
  for (int e = tid; e < 64 * 64; e += 256) {
    int mi = e >> 6, i = e & 63;
    int gmm = mh * 64 + mi; if (gmm > 126) gmm = 126;
    size_t idx2 = ((size_t)gmm * 64 + l) * 64 + i;
    Br_[mi * 65 + i] = a.flmA_re[idx2] + a.flmB_re[idx2];
    Bi_[mi * 65 + i] = a.flmA_im[idx2] + a.flmB_im[idx2];
  }
  __syncthreads();
  int o0 = oh * 32 + og * 2;
  float b0[2] = {a.scb[o0], a.scb[o0 + 1]};
  float sr[4][2], si[4][2], hr[4][2], hi[4][2];
#pragma unroll
  for (int jm = 0; jm < 4; ++jm)
#pragma unroll
    for (int qo = 0; qo < 2; ++qo) {
      sr[jm][qo] = b0[qo]; si[jm][qo] = 0.f; hr[jm][qo] = 0.f; hi[jm][qo] = 0.f;
    }
#pragma unroll 4
  for (int k = 0; k < 64; ++k) {
    float2 ar2 = *(const float2*)&Ar_[k * 32 + og * 2];
    float2 ai2 = *(const float2*)&Ai_[k * 32 + og * 2];
    float2 mv2 = *(const float2*)&Msh[k * 32 + og * 2];
    float br4[4], bi4[4];
#pragma unroll
    for (int jm = 0; jm < 4; ++jm) {
      br4[jm] = Br_[(mg * 4 + jm) * 65 + k];
      bi4[jm] = Bi_[(mg * 4 + jm) * 65 + k];
    }
    float arv[2] = {ar2.x, ar2.y}, aiv[2] = {ai2.x, ai2.y}, mvv[2] = {mv2.x, mv2.y};
#pragma unroll
    for (int jm = 0; jm < 4; ++jm)
#pragma unroll
      for (int qo = 0; qo < 2; ++qo) {
        sr[jm][qo] = fmaf(br4[jm], arv[qo], sr[jm][qo]);
        sr[jm][qo] = fmaf(-bi4[jm], aiv[qo], sr[jm][qo]);
        si[jm][qo] = fmaf(br4[jm], aiv[qo], si[jm][qo]);
        si[jm][qo] = fmaf(bi4[jm], arv[qo], si[jm][qo]);
        hr[jm][qo] = fmaf(br4[jm], mvv[qo], hr[jm][qo]);
        hi[jm][qo] = fmaf(bi4[jm], mvv[qo], hi[jm][qo]);
      }
  }
  float bb[2] = {a.bias2[o0], a.bias2[o0 + 1]};
  __syncthreads();
#pragma unroll
  for (int jm = 0; jm < 4; ++jm) {
    int gmm = mh * 64 + mg * 4 + jm;
    if (gmm > 126) continue;
    if (gmm == 63) {
#pragma unroll
      for (int qo = 0; qo < 2; ++qo)
        hr[jm][qo] = fmaf(255.0f * slv, bb[qo], hr[jm][qo]);
    }
    size_t row = ((size_t)gmm * 64 + l) * 64 + o0;
    *(float2*)(a.s_re + row) = make_float2(sr[jm][0], sr[jm][1]);
    *(float2*)(a.s_im + row) = make_float2(si[jm][0], si[jm][1]);
    *(float2*)(a.h_re + row) = make_float2(hr[jm][0], hr[jm][1]);
    *(float2*)(a.h_im + row) = make_float2(hi[jm][0], hi[jm][1]);
  }
}

__device__ __forceinline__ void proji_block(int idx, int tid, const AllArgs& a, char* sm) {
  float* Dsh = (float*)sm;            // [64][64]
  float* Br_ = (float*)(sm + 16384);  // [64][32]
  float* Bi_ = (float*)(sm + 24576);
  int mm = idx >> 2, br = (idx >> 1) & 1, ch = idx & 1;
  const float* ire = br ? a.h_re : a.s_re;
  const float* iim = br ? a.h_im : a.s_im;
  float* ore = br ? a.foh_re : a.fos_re;
  float* oim = br ? a.foh_im : a.fos_im;
  int cg_ = tid & 15, tg = tid >> 4;
  for (int e = tid; e < 64 * 64; e += 256) {
    int r = e >> 6, tt = e & 63;
    Dsh[r * 64 + tt] = a.Dinv[((size_t)mm * 64 + r) * 64 + tt];
  }
  for (int e = tid; e < 64 * 32; e += 256) {
    int r = e >> 5, cc = e & 31;
    size_t idx2 = ((size_t)mm * 64 + r) * 64 + ch * 32 + cc;
    Br_[r * 32 + cc] = ire[idx2];
    Bi_[r * 32 + cc] = iim[idx2];
  }
  __syncthreads();
  float ar[4][2], ai[4][2];
#pragma unroll
  for (int j = 0; j < 4; ++j)
#pragma unroll
    for (int q = 0; q < 2; ++q) { ar[j][q] = 0.f; ai[j][q] = 0.f; }
#pragma unroll 4
  for (int k = 0; k < 64; ++k) {
    float4 d4 = *(const float4*)&Dsh[k * 64 + tg * 4];
    float2 fr2 = *(const float2*)&Br_[k * 32 + cg_ * 2];
    float2 fi2 = *(const float2*)&Bi_[k * 32 + cg_ * 2];
    float dv[4] = {d4.x, d4.y, d4.z, d4.w};
    float frv[2] = {fr2.x, fr2.y}, fiv[2] = {fi2.x, fi2.y};
#pragma unroll
    for (int j = 0; j < 4; ++j)
#pragma unroll
      for (int q = 0; q < 2; ++q) {
        ar[j][q] = fmaf(dv[j], frv[q], ar[j][q]);
        ai[j][q] = fmaf(dv[j], fiv[q], ai[j][q]);
      }
  }
  __syncthreads();
#pragma unroll
  for (int j = 0; j < 4; ++j) {
    int t = tg * 4 + j;
    size_t ob = ((size_t)t * 127 + mm) * 64 + ch * 32 + cg_ * 2;
    *(float2*)(ore + ob) = make_float2(ar[j][0], ar[j][1]);
    *(float2*)(oim + ob) = make_float2(ai[j][0], ai[j][1]);
  }
}

__device__ __forceinline__ void idft_block(int idx, int tid, const AllArgs& a, char* sm) {
  float* Ar_ = (float*)sm;            // [32][64]
  float* Ai_ = (float*)(sm + 8192);
  float* Br_ = (float*)(sm + 16384);
  float* Bi_ = (float*)(sm + 24576);
  int t = idx >> 3, br = (idx >> 2) & 1, z = idx & 3;
  int ph = z >> 1, kh = z & 1;
  const float* fre = br ? a.foh_re : a.fos_re;
  const float* fim = br ? a.foh_im : a.fos_im;
  float* outp = br ? (kh ? a.hsbB : a.hsbA) : (kh ? a.xsbB : a.xsbA);
  int kbase = kh * 64;
  int Ktot = kh ? 63 : 64;
  int cg_ = tid & 15, pg = tid >> 4;
  float acc[4][4];
#pragma unroll
  for (int j = 0; j < 4; ++j)
#pragma unroll
    for (int q = 0; q < 4; ++q) acc[j][q] = 0.f;
  for (int k0 = 0; k0 < Ktot; k0 += 32) {
    int kn = (Ktot - k0 < 32) ? Ktot - k0 : 32;
    __syncthreads();
    for (int e = tid; e < 32 * 64; e += 256) {
      int r = e >> 6, j = e & 63;
      if (r < kn) {
        int gmm = kbase + k0 + r;
        int gp = ph * 64 + j; if (gp > 126) gp = 126;
        float ang = CN127F * (float)((gmm - 63) * gp);
        float sv, cv;
        __sincosf(ang, &sv, &cv);
        Ar_[r * 64 + j] = cv; Ai_[r * 64 + j] = sv;
        size_t bidx = ((size_t)t * 127 + gmm) * 64 + j;
        Br_[r * 64 + j] = fre[bidx]; Bi_[r * 64 + j] = fim[bidx];
      }
    }
    __syncthreads();
#pragma unroll 4
    for (int k = 0; k < kn; ++k) {
      float4 a_r = *(const float4*)&Ar_[k * 64 + pg * 4];
      float4 a_i = *(const float4*)&Ai_[k * 64 + pg * 4];
      float4 b_r = *(const float4*)&Br_[k * 64 + cg_ * 4];
      float4 b_i = *(const float4*)&Bi_[k * 64 + cg_ * 4];
      float arv[4] = {a_r.x, a_r.y, a_r.z, a_r.w};
      float aiv[4] = {a_i.x, a_i.y, a_i.z, a_i.w};
      float brv[4] = {b_r.x, b_r.y, b_r.z, b_r.w};
      float biv[4] = {b_i.x, b_i.y, b_i.z, b_i.w};
#pragma unroll
      for (int j = 0; j < 4; ++j)
#pragma unroll
        for (int q = 0; q < 4; ++q) {
          acc[j][q] = fmaf(brv[q], arv[j], acc[j][q]);
          acc[j][q] = fmaf(biv[q], -aiv[j], acc[j][q]);
        }
    }
  }
  __syncthreads();
#pragma unroll
  for (int j = 0; j < 4; ++j) {
    int gp = ph * 64 + pg * 4 + j;
    if (gp > 126) continue;
    *(float4*)(outp + ((size_t)t * 127 + gp) * 64 + cg_ * 4) =
        make_float4(acc[j][0], acc[j][1], acc[j][2], acc[j][3]);
  }
}

__device__ __forceinline__ void fin_block(int idx, int tid, const AllArgs& a) {
  int w = tid >> 6, lane = tid & 63;
  float cbv = a.c2b[lane] + a.tv[64 + lane];
  float lnsv = a.lns[lane], lnbv = a.lnb[lane];
#pragma unroll
  for (int rr = 0; rr < 4; ++rr) {
    size_t row = (size_t)idx * 16 + rr * 4 + w;  // < 8128
    size_t base2 = row * 64 + lane;
    float hv = a.hsbA[base2] + a.hsbB[base2];
    float xv = a.xsbA[base2] + a.xsbB[base2];
    float acc = cbv;
#pragma unroll 16
    for (int i = 0; i < 64; ++i)
      acc = fmaf(__shfl(hv, i, 64), a.c2w[i * 64 + lane], acc);
    float ss = wave_sum64(xv * xv);
    xv = xv / (sqrtf(ss) + 1e-6f);
    float y = xv + acc;
    float g = gelu_tanh(y);
    float mu = wave_sum64(g) * (1.0f / 64.0f);
    float d = g - mu;
    float var = wave_sum64(d * d) * (1.0f / 64.0f);
    a.out[base2] = d * rsqrtf(var + 1e-6f) * lnsv + lnbv;
  }
}

__global__ __launch_bounds__(256, 2) void ct_all(AllArgs a) {
  cg::grid_group grid = cg::this_grid();
  __shared__ __align__(16) char sm[57856];
  int tid = threadIdx.x;
  int nb = gridDim.x;
  // ---- S0: wigner(255) + A2(64) + M(64) + tv(1) + dft(512) ----
  for (int vb = blockIdx.x; vb < 896; vb += nb) {
    if (vb < 255) wigner_block(vb, tid, a, sm);
    else if (vb < 319) a2_block(vb - 255, tid, a, sm);
    else if (vb < 383) m_block(vb - 319, tid, a, sm);
    else if (vb < 384) tv_block(tid, a, sm);
    else dft_block(vb - 384, tid, a, sm);
    __syncthreads();
  }
  grid.sync();
  // ---- S1: projf(508) ----
  for (int vb = blockIdx.x; vb < 508; vb += nb) { projf_block(vb, tid, a, sm); __syncthreads(); }
  grid.sync();
  // ---- S2: mix(256) ----
  for (int vb = blockIdx.x; vb < 256; vb += nb) { mix_block(vb, tid, a, sm); __syncthreads(); }
  grid.sync();
  // ---- S3: proji(508) ----
  for (int vb = blockIdx.x; vb < 508; vb += nb) { proji_block(vb, tid, a, sm); __syncthreads(); }
  grid.sync();
  // ---- S4: idft(512) ----
  for (int vb = blockIdx.x; vb < 512; vb += nb) { idft_block(vb, tid, a, sm); __syncthreads(); }
  grid.sync();
  // ---- S5: fin(508) ----
  for (int vb = blockIdx.x; vb < 508; vb += nb) fin_block(vb, tid, a);
}

// ======================= fallback (round-7) kernels =======================
__global__ __launch_bounds__(256) void ct_setup(
    float* __restrict__ Deff, float* __restrict__ Dinv,
    float2* __restrict__ T255, float2* __restrict__ T127,
    const float* __restrict__ temb, const float* __restrict__ trw,
    const float* __restrict__ trb, const float* __restrict__ tiw,
    const float* __restrict__ tib, const float* __restrict__ stw,
    const float* __restrict__ stb, float* tcr, float* tci, float* tv) {
  int b = blockIdx.x;
  int tid = threadIdx.x;
  if (b >= 255) {
    if (b == 445) {
      if (tid < 64) {
        float ar = trb[tid], ai = tib[tid];
        for (int k = 0; k < 256; ++k) {
          float e = temb[k];
          ar = fmaf(e, trw[k * 64 + tid], ar);
          ai = fmaf(e, tiw[k * 64 + tid], ai);
        }
        tcr[tid] = ar; tci[tid] = ai;
      } else if (tid < 192) {
        int j = tid - 64;
        float aa = stb[j];
        for (int k = 0; k < 256; ++k) aa = fmaf(temb[k], stw[k * 128 + j], aa);
        tv[j] = aa;
      }
    } else {
      int id = (b - 255) * 256 + tid;
      if (id < 255 * 127) {
        int p = id / 127, mm = id % 127;
        double ang = 2.0 * DPI * (double)((mm - 63) * p) / 255.0;
        T255[id] = make_float2((float)cos(ang), (float)(-sin(ang)));
      }
      if (id < 127 * 127) {
        int mm = id / 127, p = id % 127;
        double ang = 2.0 * DPI * (double)((mm - 63) * p) / 127.0;
        T127[id] = make_float2((float)cos(ang), (float)sin(ang));
      }
    }
    return;
  }
  __shared__ double red[64];
  __shared__ float clf[64];
  int mode = (b < 128) ? 0 : 1;
  if (tid < 64) clf[tid] = (float)(-sqrt((2.0 * tid + 1.0) / (4.0 * DPI)));
  int t, mm;
  if (mode == 0) { t = b; mm = tid; }
  else { mm = b - 128; t = tid; }
  double denomN = (mode == 0) ? 255.0 : 127.0;
  double beta = (2.0 * t + 1.0) * DPI / denomN;
  float coeff;
  if (mode == 0) {
    if (tid < 63) {
      int k = 2 * (tid + 1);
      red[tid] = 8.0 * cos((double)k * beta) / (1.0 - (double)k * (double)k);
    } else if (tid == 63) {
      red[63] = 4.0;
    }
    __syncthreads();
    for (int s = 32; s > 0; s >>= 1) {
      if (tid < s) red[tid] += red[tid + s];
      __syncthreads();
    }
    double s = red[0] / 255.0;
    if (t == 127) s *= 0.5;
    coeff = (float)(s * (2.0 * DPI / 255.0));
    if (tid >= 127) return;
  } else {
    __syncthreads();
    coeff = 1.0f;
    if (tid >= 64) return;
  }
  int m = mm - 63;
  double cb = cos(beta);
  double ch = cos(0.5 * beta), sh = sin(0.5 * beta);
  int am = (m < 0) ? -m : m;
  int l0v = (am > 1) ? am : 1;
  double seed;
  if (m >= 1) {
    double j = (double)m;
    double K = exp(0.5 * (lgamma(2.0 * j + 1.0) - lgamma(j) - lgamma(j + 2.0)));
    double sgn = ((m + 1) & 1) ? -1.0 : 1.0;
    seed = sgn * K * pow(ch, j - 1.0) * pow(sh, j + 1.0);
  } else if (m <= -1) {
    double j = (double)(-m);
    double K = exp(0.5 * (lgamma(2.0 * j + 1.0) - lgamma(j) - lgamma(j + 2.0)));
    seed = K * pow(ch, j + 1.0) * pow(sh, j - 1.0);
  } else {
    seed = -sqrt(2.0) * sh * ch;
  }
  float dl = (float)seed, dm1 = 0.0f, S_cur = 0.0f;
  float cbf = (float)cb, mf = (float)m;
  for (int l = 0; l < 64; ++l) {
    float val = 0.0f;
    if (l >= l0v) {
      val = dl * coeff * clf[l];
      float Ld = (float)l, lp = Ld + 1.0f;
      float S_next = sqrtf((lp * lp - mf * mf) * (lp * lp - 1.0f));
      float num1 = (2.0f * Ld + 1.0f) * (Ld * lp * cbf + mf);
      float dn = (num1 * dl - lp * S_cur * dm1) / (Ld * S_next);
      dm1 = dl; dl = dn; S_cur = S_next;
    }
    if (mode == 0) Deff[((size_t)t * 127 + mm) * 64 + l] = val;
    else Dinv[((size_t)mm * 64 + l) * 64 + t] = val;
  }
}

__global__ void ct_AM(const float* __restrict__ cw, const float* __restrict__ wr,
                      const float* __restrict__ wi, const float* __restrict__ tcr,
                      const float* __restrict__ tci, const float* __restrict__ c1w,
                      const float* __restrict__ c1b, const float* __restrict__ sw,
                      const float* __restrict__ tv, const float* __restrict__ Deff,
                      float2* __restrict__ A2, float* __restrict__ Mm,
                      float* __restrict__ bias2, float* __restrict__ Sl) {
  int b = blockIdx.x, o = threadIdx.x;
  if (b < 64) {
    int l = b;
    float tr = tcr[l], ti = tci[l];
    for (int i = 0; i < 64; ++i) {
      int idx = (l * 64 + i) * 64 + o;
      float r = wr[idx], s = wi[idx];
      A2[idx] = make_float2(cw[i * 64 + o] + tr * r - ti * s, tr * s + ti * r);
    }
  } else if (b < 128) {
    int j = b - 64;
    float wt = tv[o];
    float acc = 0.f;
    for (int i = 0; i < 64; ++i) acc = fmaf(c1w[j * 64 + i], sw[i * 64 + o], acc);
    Mm[j * 64 + o] = wt * acc;
    if (j == 0) {
      float bb = 0.f;
      for (int i = 0; i < 64; ++i) bb = fmaf(c1b[i], sw[i * 64 + o], bb);
      bias2[o] = wt * bb;
    }
  } else {
    int l = o;
    float s = 0.f;
    for (int t = 0; t < 128; ++t) s += Deff[((size_t)t * 127 + 63) * 64 + l];
    Sl[l] = s;
  }
}

__global__ __launch_bounds__(256) void ct_dft_fb(const float* __restrict__ x,
                                                 const float2* __restrict__ T255,
                                                 float* __restrict__ Are, float* __restrict__ Aim,
                                                 float* __restrict__ Bre, float* __restrict__ Bim) {
  __shared__ float xs_[64][64];
  __shared__ float tsr[64][64], tsi[64][64];
  int t = blockIdx.x, mh = blockIdx.y, ph = blockIdx.z;
  float* ore = ph ? Bre : Are;
  float* oim = ph ? Bim : Aim;
  int pbase = ph * 128;
  int Ktot = ph ? 127 : 128;
  int tid = threadIdx.x;
  int cg_ = tid & 15, mg = tid >> 4;
  float accr[4][4], acci[4][4];
#pragma unroll
  for (int j = 0; j < 4; ++j)
#pragma unroll
    for (int q = 0; q < 4; ++q) { accr[j][q] = 0.f; acci[j][q] = 0.f; }
  for (int k0 = 0; k0 < Ktot; k0 += 64) {
    int kn = (Ktot - k0 < 64) ? Ktot - k0 : 64;
    __syncthreads();
    {
      int r = tid >> 2, c4 = (tid & 3) * 16;
      if (r < kn) {
        const float4* src = (const float4*)(x + ((size_t)t * 255 + pbase + k0 + r) * 64 + c4);
        float4* dst = (float4*)&xs_[r][c4];
        dst[0] = src[0]; dst[1] = src[1]; dst[2] = src[2]; dst[3] = src[3];
      }
    }
    for (int e = tid; e < 64 * 64; e += 256) {
      int r = e >> 6, mi = e & 63;
      if (r < kn) {
        int gcol = mh * 64 + mi; if (gcol > 126) gcol = 126;
        float2 tw = T255[(size_t)(pbase + k0 + r) * 127 + gcol];
        tsr[r][mi] = tw.x; tsi[r][mi] = tw.y;
      }
    }
    __syncthreads();
#pragma unroll 4
    for (int k = 0; k < kn; ++k) {
      float4 xv = *(const float4*)&xs_[k][cg_ * 4];
      float4 tr4 = *(const float4*)&tsr[k][mg * 4];
      float4 ti4 = *(const float4*)&tsi[k][mg * 4];
      float xv4[4] = {xv.x, xv.y, xv.z, xv.w};
      float trv[4] = {tr4.x, tr4.y, tr4.z, tr4.w};
      float tiv[4] = {ti4.x, ti4.y, ti4.z, ti4.w};
#pragma unroll
      for (int j = 0; j < 4; ++j)
#pragma unroll
        for (int q = 0; q < 4; ++q) {
          accr[j][q] = fmaf(xv4[q], trv[j], accr[j][q]);
          acci[j][q] = fmaf(xv4[q], tiv[j], acci[j][q]);
        }
    }
  }
#pragma unroll
  for (int j = 0; j < 4; ++j) {
    int gmm = mh * 64 + mg * 4 + j;
    if (gmm > 126) continue;
    size_t ob = ((size_t)t * 127 + gmm) * 64 + cg_ * 4;
    *(float4*)(ore + ob) = make_float4(accr[j][0], accr[j][1], accr[j][2], accr[j][3]);
    *(float4*)(oim + ob) = make_float4(acci[j][0], acci[j][1], acci[j][2], acci[j][3]);
  }
}

__global__ __launch_bounds__(256) void ct_projf_fb(const float* __restrict__ Deff,
                                                   const float* __restrict__ fAre,
                                                   const float* __restrict__ fAim,
                                                   const float* __restrict__ fBre,
                                                   const float* __restrict__ fBim,
                                                   float* __restrict__ flmA_re, float* __restrict__ flmA_im,
                                                   float* __restrict__ flmB_re, float* __restrict__ flmB_im) {
  __shared__ float Dsh[64][32];
  __shared__ float fr_[64][64], fi_[64][64];
  int mm = blockIdx.x, lh = blockIdx.y, th = blockIdx.z;
  float* ore = th ? flmB_re : flmA_re;
  float* oim = th ? flmB_im : flmA_im;
  int tb = th * 64;
  int tid = threadIdx.x;
  int cg_ = tid & 15, lg = tid >> 4;
  for (int e = tid; e < 64 * 32; e += 256) {
    int r = e >> 5, li = e & 31;
    Dsh[r][li] = Deff[((size_t)(tb + r) * 127 + mm) * 64 + lh * 32 + li];
  }
  for (int e = tid; e < 64 * 64; e += 256) {
    int r = e >> 6, c = e & 63;
    size_t idx = ((size_t)(tb + r) * 127 + mm) * 64 + c;
    fr_[r][c] = fAre[idx] + fBre[idx];
    fi_[r][c] = fAim[idx] + fBim[idx];
  }
  __syncthreads();
  float ar[2][4], ai[2][4];
#pragma unroll
  for (int li = 0; li < 2; ++li)
#pragma unroll
    for (int q = 0; q < 4; ++q) { ar[li][q] = 0.f; ai[li][q] = 0.f; }
#pragma unroll 4
  for (int k = 0; k < 64; ++k) {
    float4 fr4 = *(const float4*)&fr_[k][cg_ * 4];
    float4 fi4 = *(const float4*)&fi_[k][cg_ * 4];
    float2 d2 = *(const float2*)&Dsh[k][lg * 2];
    float frv[4] = {fr4.x, fr4.y, fr4.z, fr4.w};
    float fiv[4] = {fi4.x, fi4.y, fi4.z, fi4.w};
    float dv[2] = {d2.x, d2.y};
#pragma unroll
    for (int li = 0; li < 2; ++li)
#pragma unroll
      for (int q = 0; q < 4; ++q) {
        ar[li][q] = fmaf(dv[li], frv[q], ar[li][q]);
        ai[li][q] = fmaf(dv[li], fiv[q], ai[li][q]);
      }
  }
#pragma unroll
  for (int li = 0; li < 2; ++li) {
    size_t row = ((size_t)mm * 64 + lh * 32 + lg * 2 + li) * 64 + cg_ * 4;
    *(float4*)(ore + row) = make_float4(ar[li][0], ar[li][1], ar[li][2], ar[li][3]);
    *(float4*)(oim + row) = make_float4(ai[li][0], ai[li][1], ai[li][2], ai[li][3]);
  }
}

__global__ __launch_bounds__(256) void ct_mix_fb(const float* __restrict__ flmA_re,
                                                 const float* __restrict__ flmA_im,
                                                 const float* __restrict__ flmB_re,
                                                 const float* __restrict__ flmB_im,
                                                 const float2* __restrict__ A2,
                                                 const float* __restrict__ Mm,
                                                 const float* __restrict__ scb,
                                                 const float* __restrict__ bias2,
                                                 const float* __restrict__ Sl,
                                                 float* __restrict__ s_re, float* __restrict__ s_im,
                                                 float* __restrict__ h_re, float* __restrict__ h_im) {
  __shared__ float Ar_[64][32], Ai_[64][32], Msh[64][32];
  __shared__ float Br_[64][65], Bi_[64][65];
  int l = blockIdx.x, mh = blockIdx.y, oh = blockIdx.z;
  int tid = threadIdx.x;
  int og = tid & 15, mg = tid >> 4;
  for (int e = tid; e < 64 * 32; e += 256) {
    int r = e >> 5, oi = e & 31;
    float2 aa = A2[((size_t)l * 64 + r) * 64 + oh * 32 + oi];
    Ar_[r][oi] = aa.x; Ai_[r][oi] = aa.y;
    Msh[r][oi] = Mm[r * 64 + oh * 32 + oi];
  }
  for (int e = tid; e < 64 * 64; e += 256) {
    int mi = e >> 6, i = e & 63;
    int gmm = mh * 64 + mi; if (gmm > 126) gmm = 126;
    size_t idx = ((size_t)gmm * 64 + l) * 64 + i;
    Br_[mi][i] = flmA_re[idx] + flmB_re[idx];
    Bi_[mi][i] = flmA_im[idx] + flmB_im[idx];
  }
  __syncthreads();
  int o0 = oh * 32 + og * 2;
  float b0[2] = {scb[o0], scb[o0 + 1]};
  float sr[4][2], si[4][2], hr[4][2], hi[4][2];
#pragma unroll
  for (int jm = 0; jm < 4; ++jm)
#pragma unroll
    for (int qo = 0; qo < 2; ++qo) {
      sr[jm][qo] = b0[qo]; si[jm][qo] = 0.f; hr[jm][qo] = 0.f; hi[jm][qo] = 0.f;
    }
#pragma unroll 4
  for (int k = 0; k < 64; ++k) {
    float2 ar2 = *(const float2*)&Ar_[k][og * 2];
    float2 ai2 = *(const float2*)&Ai_[k][og * 2];
    float2 mv2 = *(const float2*)&Msh[k][og * 2];
    float br4[4], bi4[4];
#pragma unroll
    for (int jm = 0; jm < 4; ++jm) {
      br4[jm] = Br_[mg * 4 + jm][k];
      bi4[jm] = Bi_[mg * 4 + jm][k];
    }
    float arv[2] = {ar2.x, ar2.y}, aiv[2] = {ai2.x, ai2.y}, mvv[2] = {mv2.x, mv2.y};
#pragma unroll
    for (int jm = 0; jm < 4; ++jm)
#pragma unroll
      for (int qo = 0; qo < 2; ++qo) {
        sr[jm][qo] = fmaf(br4[jm], arv[qo], sr[jm][qo]);
        sr[jm][qo] = fmaf(-bi4[jm], aiv[qo], sr[jm][qo]);
        si[jm][qo] = fmaf(br4[jm], aiv[qo], si[jm][qo]);
        si[jm][qo] = fmaf(bi4[jm], arv[qo], si[jm][qo]);
        hr[jm][qo] = fmaf(br4[jm], mvv[qo], hr[jm][qo]);
        hi[jm][qo] = fmaf(bi4[jm], mvv[qo], hi[jm][qo]);
      }
  }
  float Slv = Sl[l];
  float bb[2] = {bias2[o0], bias2[o0 + 1]};
#pragma unroll
  for (int jm = 0; jm < 4; ++jm) {
    int gmm = mh * 64 + mg * 4 + jm;
    if (gmm > 126) continue;
    if (gmm == 63) {
#pragma unroll
      for (int qo = 0; qo < 2; ++qo)
        hr[jm][qo] = fmaf(255.0f * Slv, bb[qo], hr[jm][qo]);
    }
    size_t row = ((size_t)gmm * 64 + l) * 64 + o0;
    *(float2*)(s_re + row) = make_float2(sr[jm][0], sr[jm][1]);
    *(float2*)(s_im + row) = make_float2(si[jm][0], si[jm][1]);
    *(float2*)(h_re + row) = make_float2(hr[jm][0], hr[jm][1]);
    *(float2*)(h_im + row) = make_float2(hi[jm][0], hi[jm][1]);
  }
}

__global__ __launch_bounds__(256) void ct_proji_fb(const float* __restrict__ Dinv,
                                                   const float* __restrict__ s_re,
                                                   const float* __restrict__ s_im,
                                                   const float* __restrict__ h_re,
                                                   const float* __restrict__ h_im,
                                                   float* __restrict__ fos_re, float* __restrict__ fos_im,
                                                   float* __restrict__ foh_re, float* __restrict__ foh_im) {
  __shared__ float Dsh[64][64];
  __shared__ float Br_[64][32], Bi_[64][32];
  int mm = blockIdx.x, br = blockIdx.y, ch = blockIdx.z;
  const float* ire = br ? h_re : s_re;
  const float* iim = br ? h_im : s_im;
  float* ore = br ? foh_re : fos_re;
  float* oim = br ? foh_im : fos_im;
  int tid = threadIdx.x;
  int cg_ = tid & 15, tg = tid >> 4;
  for (int e = tid; e < 64 * 64; e += 256) {
    int r = e >> 6, tt = e & 63;
    Dsh[r][tt] = Dinv[((size_t)mm * 64 + r) * 64 + tt];
  }
  for (int e = tid; e < 64 * 32; e += 256) {
    int r = e >> 5, cc = e & 31;
    size_t idx = ((size_t)mm * 64 + r) * 64 + ch * 32 + cc;
    Br_[r][cc] = ire[idx];
    Bi_[r][cc] = iim[idx];
  }
  __syncthreads();
  float ar[4][2], ai[4][2];
#pragma unroll
  for (int j = 0; j < 4; ++j)
#pragma unroll
    for (int q = 0; q < 2; ++q) { ar[j][q] = 0.f; ai[j][q] = 0.f; }
#pragma unroll 4
  for (int k = 0; k < 64; ++k) {
    float4 d4 = *(const float4*)&Dsh[k][tg * 4];
    float2 fr2 = *(const float2*)&Br_[k][cg_ * 2];
    float2 fi2 = *(const float2*)&Bi_[k][cg_ * 2];
    float dv[4] = {d4.x, d4.y, d4.z, d4.w};
    float frv[2] = {fr2.x, fr2.y}, fiv[2] = {fi2.x, fi2.y};
#pragma unroll
    for (int j = 0; j < 4; ++j)
#pragma unroll
      for (int q = 0; q < 2; ++q) {
        ar[j][q] = fmaf(dv[j], frv[q], ar[j][q]);
        ai[j][q] = fmaf(dv[j], fiv[q], ai[j][q]);
      }
  }
#pragma unroll
  for (int j = 0; j < 4; ++j) {
    int t = tg * 4 + j;
    size_t ob = ((size_t)t * 127 + mm) * 64 + ch * 32 + cg_ * 2;
    *(float2*)(ore + ob) = make_float2(ar[j][0], ar[j][1]);
    *(float2*)(oim + ob) = make_float2(ai[j][0], ai[j][1]);
  }
}

__global__ __launch_bounds__(256) void ct_idft_fb(const float2* __restrict__ T127,
                                                  const float* __restrict__ fos_re,
                                                  const float* __restrict__ fos_im,
                                                  const float* __restrict__ foh_re,
                                                  const float* __restrict__ foh_im,
                                                  float* __restrict__ xsbA, float* __restrict__ xsbB,
                                                  float* __restrict__ hsbA, float* __restrict__ hsbB) {
  __shared__ float Ar_[32][64], Ai_[32][64], Br_[32][64], Bi_[32][64];
  int t = blockIdx.x, br = blockIdx.y;
  int z = blockIdx.z;
  int ph = z >> 1, kh = z & 1;
  const float* fre = br ? foh_re : fos_re;
  const float* fim = br ? foh_im : fos_im;
  float* outp = br ? (kh ? hsbB : hsbA) : (kh ? xsbB : xsbA);
  int kbase = kh * 64;
  int Ktot = kh ? 63 : 64;
  int tid = threadIdx.x;
  int cg_ = tid & 15, pg = tid >> 4;
  float acc[4][4];
#pragma unroll
  for (int j = 0; j < 4; ++j)
#pragma unroll
    for (int q = 0; q < 4; ++q) acc[j][q] = 0.f;
  for (int k0 = 0; k0 < Ktot; k0 += 32) {
    int kn = (Ktot - k0 < 32) ? Ktot - k0 : 32;
    __syncthreads();
    for (int e = tid; e < 32 * 64; e += 256) {
      int r = e >> 6, j = e & 63;
      if (r < kn) {
        int gmm = kbase + k0 + r;
        int gp = ph * 64 + j; if (gp > 126) gp = 126;
        float2 tw = T127[(size_t)gmm * 127 + gp];
        Ar_[r][j] = tw.x; Ai_[r][j] = tw.y;
        size_t bidx = ((size_t)t * 127 + gmm) * 64 + j;
        Br_[r][j] = fre[bidx]; Bi_[r][j] = fim[bidx];
      }
    }
    __syncthreads();
#pragma unroll 4
    for (int k = 0; k < kn; ++k) {
      float4 a_r = *(const float4*)&Ar_[k][pg * 4];
      float4 a_i = *(const float4*)&Ai_[k][pg * 4];
      float4 b_r = *(const float4*)&Br_[k][cg_ * 4];
      float4 b_i = *(const float4*)&Bi_[k][cg_ * 4];
      float arv[4] = {a_r.x, a_r.y, a_r.z, a_r.w};
      float aiv[4] = {a_i.x, a_i.y, a_i.z, a_i.w};
      float brv[4] = {b_r.x, b_r.y, b_r.z, b_r.w};
      float biv[4] = {b_i.x, b_i.y, b_i.z, b_i.w};
#pragma unroll
      for (int j = 0; j < 4; ++j)
#pragma unroll
        for (int q = 0; q < 4; ++q) {
          acc[j][q] = fmaf(brv[q], arv[j], acc[j][q]);
          acc[j][q] = fmaf(biv[q], -aiv[j], acc[j][q]);
        }
    }
  }
#pragma unroll
  for (int j = 0; j < 4; ++j) {
    int gp = ph * 64 + pg * 4 + j;
    if (gp > 126) continue;
    *(float4*)(outp + ((size_t)t * 127 + gp) * 64 + cg_ * 4) =
        make_float4(acc[j][0], acc[j][1], acc[j][2], acc[j][3]);
  }
}

__global__ __launch_bounds__(256) void ct_fin_fb(const float* __restrict__ xsbA,
                                                 const float* __restrict__ xsbB,
                                                 const float* __restrict__ hsbA,
                                                 const float* __restrict__ hsbB,
                                                 const float* __restrict__ c2w,
                                                 const float* __restrict__ c2b,
                                                 const float* __restrict__ tv,
                                                 const float* __restrict__ lns,
                                                 const float* __restrict__ lnb,
                                                 float* __restrict__ out) {
  int w = threadIdx.x >> 6, lane = threadIdx.x & 63;
  size_t row = (size_t)blockIdx.x * 4 + w;
  size_t base = row * 64 + lane;
  float hv = hsbA[base] + hsbB[base];
  float xv = xsbA[base] + xsbB[base];
  float acc = c2b[lane] + tv[64 + lane];
#pragma unroll 16
  for (int i = 0; i < 64; ++i)
    acc = fmaf(__shfl(hv, i, 64), c2w[i * 64 + lane], acc);
  float ss = wave_sum64(xv * xv);
  xv = xv / (sqrtf(ss) + 1e-6f);
  float y = xv + acc;
  float g = gelu_tanh(y);
  float mu = wave_sum64(g) * (1.0f / 64.0f);
  float d = g - mu;
  float var = wave_sum64(d * d) * (1.0f / 64.0f);
  out[base] = d * rsqrtf(var + 1e-6f) * lns[lane] + lnb[lane];
}

// ---------------- host launcher ----------------
extern "C" void kernel_launch(void* const* d_in, const int* in_sizes, int n_in,
                              void* d_out, int out_size, void* d_ws, size_t ws_size,
                              hipStream_t stream) {
  const float* x = (const float*)d_in[0];
  const float* temb = (const float*)d_in[1];
  const float* scw = (const float*)d_in[2];
  const float* scb = (const float*)d_in[3];
  const float* swr = (const float*)d_in[4];
  const float* swi = (const float*)d_in[5];
  const float* strw = (const float*)d_in[6];
  const float* strb = (const float*)d_in[7];
  const float* stiw = (const float*)d_in[8];
  const float* stib = (const float*)d_in[9];
  const float* c1w = (const float*)d_in[10];
  const float* c1b = (const float*)d_in[11];
  const float* stw = (const float*)d_in[12];
  const float* stb = (const float*)d_in[13];
  const float* sweight = (const float*)d_in[14];
  const float* c2w = (const float*)d_in[15];
  const float* c2b = (const float*)d_in[16];
  const float* lns = (const float*)d_in[17];
  const float* lnb = (const float*)d_in[18];
  float* out = (float*)d_out;

  char* base = (char*)d_ws;
  size_t off = 0;
  auto alloc = [&](size_t bytes) -> void* {
    void* p = base + off;
    off += (bytes + 255) & ~(size_t)255;
    return p;
  };
  float* tcr = (float*)alloc(64 * sizeof(float));
  float* tci = (float*)alloc(64 * sizeof(float));
  float* tv = (float*)alloc(128 * sizeof(float));
  float* Mm = (float*)alloc(4096 * sizeof(float));
  float* bias2 = (float*)alloc(64 * sizeof(float));
  float* Sl = (float*)alloc(64 * sizeof(float));
  float2* A2 = (float2*)alloc(262144 * sizeof(float2));
  float* Deff = (float*)alloc(1040384 * sizeof(float));
  float* Dinv = (float*)alloc(520192 * sizeof(float));
  float2* T255 = (float2*)alloc(32385 * sizeof(float2));
  float2* T127 = (float2*)alloc(16129 * sizeof(float2));
  float* ftmA_re = (float*)alloc(1040384 * sizeof(float));
  float* ftmA_im = (float*)alloc(1040384 * sizeof(float));
  float* ftmB_re = (float*)alloc(1040384 * sizeof(float));
  float* ftmB_im = (float*)alloc(1040384 * sizeof(float));
  float* flmA_re = (float*)alloc(520192 * sizeof(float));
  float* flmA_im = (float*)alloc(520192 * sizeof(float));
  float* flmB_re = (float*)alloc(520192 * sizeof(float));
  float* flmB_im = (float*)alloc(520192 * sizeof(float));
  if (off > ws_size) return;
  // aliases with stage-disjoint lifetimes:
  float* s_re = ftmA_re;
  float* s_im = ftmA_im;
  float* h_re = ftmB_re;
  float* h_im = ftmB_im;
  float* fos_re = Deff;
  float* fos_im = Deff + 520192;
  float* foh_re = flmA_re;
  float* foh_im = flmA_im;
  float* xsbA = flmB_re;
  float* xsbB = flmB_im;
  float* hsbA = ftmA_re;
  float* hsbB = ftmA_im;

  AllArgs ha;
  ha.x = x; ha.temb = temb; ha.scw = scw; ha.scb = scb; ha.swr = swr; ha.swi = swi;
  ha.strw = strw; ha.strb = strb; ha.stiw = stiw; ha.stib = stib;
  ha.c1w = c1w; ha.c1b = c1b; ha.stw = stw; ha.stb = stb; ha.sweight = sweight;
  ha.c2w = c2w; ha.c2b = c2b; ha.lns = lns; ha.lnb = lnb;
  ha.out = out;
  ha.A2 = (float*)A2; ha.Mm = Mm; ha.bias2 = bias2; ha.tv = tv;
  ha.Deff = Deff; ha.Dinv = Dinv;
  ha.ftmA_re = ftmA_re; ha.ftmA_im = ftmA_im; ha.ftmB_re = ftmB_re; ha.ftmB_im = ftmB_im;
  ha.flmA_re = flmA_re; ha.flmA_im = flmA_im; ha.flmB_re = flmB_re; ha.flmB_im = flmB_im;
  ha.s_re = s_re; ha.s_im = s_im; ha.h_re = h_re; ha.h_im = h_im;
  ha.fos_re = fos_re; ha.fos_im = fos_im; ha.foh_re = foh_re; ha.foh_im = foh_im;
  ha.xsbA = xsbA; ha.xsbB = xsbB; ha.hsbA = hsbA; ha.hsbB = hsbB;

  void* kargs[] = {(void*)&ha};
  hipError_t err = hipLaunchCooperativeKernel(reinterpret_cast<void*>(&ct_all),
                                              dim3(512), dim3(256), kargs, 0, stream);
  if (err == hipSuccess) return;

  // -------- fallback: round-7 multi-kernel pipeline --------
  hipLaunchKernelGGL(ct_setup, dim3(446), dim3(256), 0, stream, Deff, Dinv, T255, T127,
                     temb, strw, strb, stiw, stib, stw, stb, tcr, tci, tv);
  hipLaunchKernelGGL(ct_AM, dim3(129), dim3(64), 0, stream, scw, swr, swi, tcr, tci,
                     c1w, c1b, sweight, tv, Deff, A2, Mm, bias2, Sl);
  hipLaunchKernelGGL(ct_dft_fb, dim3(128, 2, 2), dim3(256), 0, stream, x, T255,
                     ftmA_re, ftmA_im, ftmB_re, ftmB_im);
  hipLaunchKernelGGL(ct_projf_fb, dim3(127, 2, 2), dim3(256), 0, stream, Deff,
                     ftmA_re, ftmA_im, ftmB_re, ftmB_im,
                     flmA_re, flmA_im, flmB_re, flmB_im);
  hipLaunchKernelGGL(ct_mix_fb, dim3(64, 2, 2), dim3(256), 0, stream,
                     flmA_re, flmA_im, flmB_re, flmB_im, A2, Mm, scb, bias2, Sl,
                     s_re, s_im, h_re, h_im);
  hipLaunchKernelGGL(ct_proji_fb, dim3(127, 2, 2), dim3(256), 0, stream, Dinv,
                     s_re, s_im, h_re, h_im, fos_re, fos_im, foh_re, foh_im);
  hipLaunchKernelGGL(ct_idft_fb, dim3(64, 2, 4), dim3(256), 0, stream, T127,
                     fos_re, fos_im, foh_re, foh_im, xsbA, xsbB, hsbA, hsbB);
  hipLaunchKernelGGL(ct_fin_fb, dim3(2032), dim3(256), 0, stream, xsbA, xsbB, hsbA, hsbB,
                     c2w, c2b, tv, lns, lnb, out);
}

// Round 9
// 211.947 us; speedup vs baseline: 2.5699x; 2.5699x over previous
//
#include <hip/hip_runtime.h>
#include <math.h>

#define DPI 3.141592653589793238462643383279502884

// ---------------- device helpers ----------------
__device__ __forceinline__ float wave_sum64(float v) {
#pragma unroll
  for (int off = 32; off > 0; off >>= 1) v += __shfl_xor(v, off, 64);
  return v;
}

__device__ __forceinline__ float gelu_tanh(float v) {
  float u = 0.7978845608028654f * (v + 0.044715f * v * v * v);
  return 0.5f * v * (1.0f + tanhf(u));
}

#define CN255F ((float)(-2.0 * DPI / 255.0))
#define CN127F ((float)(2.0 * DPI / 127.0))

// ---------------- setup: Wigner tables + A2/M/bias2/tv (one launch) ----------------
// blocks 0..127   : Deff[t][mm][l] (t=b, lanes=mm; quad-weight sum lane-parallel)
// blocks 128..254 : Dinv[mm][l][t] (mm=b-128, lanes=t)
// blocks 255..318 : A2[l][i][o] (l=b-255; t-emb reduction in-block)
// blocks 319..382 : Mm[j][o] (+bias2 at j==0) (j=b-319; t-emb reduction in-block)
// block  383      : tv[128]
__global__ __launch_bounds__(256) void ct_setup(
    float* __restrict__ Deff, float* __restrict__ Dinv,
    const float* __restrict__ temb, const float* __restrict__ trw,
    const float* __restrict__ trb, const float* __restrict__ tiw,
    const float* __restrict__ tib, const float* __restrict__ stw,
    const float* __restrict__ stb, const float* __restrict__ scw,
    const float* __restrict__ swr, const float* __restrict__ swi,
    const float* __restrict__ c1w, const float* __restrict__ c1b,
    const float* __restrict__ sweight,
    float2* __restrict__ A2, float* __restrict__ Mm,
    float* __restrict__ bias2, float* __restrict__ tv) {
  __shared__ double red[64];
  __shared__ float clf[64];
  __shared__ float fb1[256];
  __shared__ float fb2[256];
  int b = blockIdx.x;
  int tid = threadIdx.x;
  if (b >= 255) {
    if (b < 319) {  // ---- A2 block, l = b-255 ----
      int l = b - 255;
      fb1[tid] = temb[tid] * trw[tid * 64 + l];
      fb2[tid] = temb[tid] * tiw[tid * 64 + l];
      __syncthreads();
      for (int s = 128; s > 0; s >>= 1) {
        if (tid < s) { fb1[tid] += fb1[tid + s]; fb2[tid] += fb2[tid + s]; }
        __syncthreads();
      }
      float tr = fb1[0] + trb[l], ti = fb2[0] + tib[l];
      int o = tid & 63, iq = tid >> 6;
      for (int i = iq * 16; i < iq * 16 + 16; ++i) {
        int idx = (l * 64 + i) * 64 + o;
        float r = swr[idx], s2 = swi[idx];
        A2[idx] = make_float2(scw[i * 64 + o] + tr * r - ti * s2, tr * s2 + ti * r);
      }
    } else if (b < 383) {  // ---- M block, j = b-319 ----
      int j = b - 319;
      int o = tid & 63, part = tid >> 6;
      float p = 0.f;
      for (int k = part * 64; k < part * 64 + 64; ++k)
        p = fmaf(temb[k], stw[k * 128 + o], p);
      fb1[part * 64 + o] = p;
      __syncthreads();
      if (part == 0) fb2[o] = fb1[o] + fb1[64 + o] + fb1[128 + o] + fb1[192 + o] + stb[o];
      __syncthreads();
      float tvo = fb2[o];
      float q = 0.f;
      for (int i = part * 16; i < part * 16 + 16; ++i)
        q = fmaf(c1w[j * 64 + i], sweight[i * 64 + o], q);
      __syncthreads();
      fb1[part * 64 + o] = q;
      __syncthreads();
      if (part == 0) Mm[j * 64 + o] = tvo * (fb1[o] + fb1[64 + o] + fb1[128 + o] + fb1[192 + o]);
      if (j == 0) {
        float bq = 0.f;
        for (int i = part * 16; i < part * 16 + 16; ++i)
          bq = fmaf(c1b[i], sweight[i * 64 + o], bq);
        __syncthreads();
        fb1[part * 64 + o] = bq;
        __syncthreads();
        if (part == 0) bias2[o] = tvo * (fb1[o] + fb1[64 + o] + fb1[128 + o] + fb1[192 + o]);
      }
    } else {  // ---- tv block ----
      int o = tid & 127, part = tid >> 7;
      float p = 0.f;
      for (int k = part * 128; k < part * 128 + 128; ++k)
        p = fmaf(temb[k], stw[k * 128 + o], p);
      fb1[part * 128 + o] = p;
      __syncthreads();
      if (part == 0) tv[o] = fb1[o] + fb1[128 + o] + stb[o];
    }
    return;
  }
  // ---- wigner ----
  int mode = (b < 128) ? 0 : 1;
  if (tid < 64) clf[tid] = (float)(-sqrt((2.0 * tid + 1.0) / (4.0 * DPI)));
  int t, mm;
  if (mode == 0) { t = b; mm = tid; }
  else { mm = b - 128; t = tid; }
  double denomN = (mode == 0) ? 255.0 : 127.0;
  double beta = (2.0 * t + 1.0) * DPI / denomN;
  float coeff;
  if (mode == 0) {
    // quad-weight pair sum (wq[t]+wq[254-t]) lane-parallel
    if (tid < 63) {
      int k = 2 * (tid + 1);
      red[tid] = 8.0 * cos((double)k * beta) / (1.0 - (double)k * (double)k);
    } else if (tid == 63) {
      red[63] = 4.0;
    }
    __syncthreads();
    for (int s = 32; s > 0; s >>= 1) {
      if (tid < s) red[tid] += red[tid + s];
      __syncthreads();
    }
    double s = red[0] / 255.0;
    if (t == 127) s *= 0.5;
    coeff = (float)(s * (2.0 * DPI / 255.0));
    if (tid >= 127) return;
  } else {
    __syncthreads();
    coeff = 1.0f;
    if (tid >= 64) return;
  }
  int m = mm - 63;
  double cb = cos(beta);
  double ch = cos(0.5 * beta), sh = sin(0.5 * beta);
  int am = (m < 0) ? -m : m;
  int l0v = (am > 1) ? am : 1;
  double seed;
  if (m >= 1) {
    double j = (double)m;
    double K = exp(0.5 * (lgamma(2.0 * j + 1.0) - lgamma(j) - lgamma(j + 2.0)));
    double sgn = ((m + 1) & 1) ? -1.0 : 1.0;
    seed = sgn * K * pow(ch, j - 1.0) * pow(sh, j + 1.0);
  } else if (m <= -1) {
    double j = (double)(-m);
    double K = exp(0.5 * (lgamma(2.0 * j + 1.0) - lgamma(j) - lgamma(j + 2.0)));
    seed = K * pow(ch, j + 1.0) * pow(sh, j - 1.0);
  } else {
    seed = -sqrt(2.0) * sh * ch;
  }
  // fp32 upward recurrence (stable: dominant-solution direction)
  float dl = (float)seed, dm1 = 0.0f, S_cur = 0.0f;
  float cbf = (float)cb, mf = (float)m;
  for (int l = 0; l < 64; ++l) {
    float val = 0.0f;
    if (l >= l0v) {
      val = dl * coeff * clf[l];
      float Ld = (float)l, lp = Ld + 1.0f;
      float S_next = sqrtf((lp * lp - mf * mf) * (lp * lp - 1.0f));
      float num1 = (2.0f * Ld + 1.0f) * (Ld * lp * cbf + mf);
      float dn = (num1 * dl - lp * S_cur * dm1) / (Ld * S_next);
      dm1 = dl; dl = dn; S_cur = S_next;
    }
    if (mode == 0) Deff[((size_t)t * 127 + mm) * 64 + l] = val;
    else Dinv[((size_t)mm * 64 + l) * 64 + t] = val;
  }
}

// ---------------- forward DFT: tiled GEMM, inline twiddles, K(p)-split ----------------
// grid (t=128, mh=2, ph=2), block 256.
__global__ __launch_bounds__(256) void ct_dft(const float* __restrict__ x,
                                              float* __restrict__ Are, float* __restrict__ Aim,
                                              float* __restrict__ Bre, float* __restrict__ Bim) {
  __shared__ float xs_[64][64];
  __shared__ float tsr[64][64], tsi[64][64];
  int t = blockIdx.x, mh = blockIdx.y, ph = blockIdx.z;
  float* ore = ph ? Bre : Are;
  float* oim = ph ? Bim : Aim;
  int pbase = ph * 128;
  int Ktot = ph ? 127 : 128;
  int tid = threadIdx.x;
  int cg_ = tid & 15, mg = tid >> 4;
  float accr[4][4], acci[4][4];
#pragma unroll
  for (int j = 0; j < 4; ++j)
#pragma unroll
    for (int q = 0; q < 4; ++q) { accr[j][q] = 0.f; acci[j][q] = 0.f; }
  for (int k0 = 0; k0 < Ktot; k0 += 64) {
    int kn = (Ktot - k0 < 64) ? Ktot - k0 : 64;
    __syncthreads();
    {
      int r = tid >> 2, c4 = (tid & 3) * 16;
      if (r < kn) {
        const float4* src = (const float4*)(x + ((size_t)t * 255 + pbase + k0 + r) * 64 + c4);
        float4* dst = (float4*)&xs_[r][c4];
        dst[0] = src[0]; dst[1] = src[1]; dst[2] = src[2]; dst[3] = src[3];
      }
    }
    for (int e = tid; e < 64 * 64; e += 256) {
      int r = e >> 6, mi = e & 63;
      if (r < kn) {
        int gcol = mh * 64 + mi; if (gcol > 126) gcol = 126;
        int p = pbase + k0 + r;
        float ang = CN255F * (float)((gcol - 63) * p);
        float sv, cv;
        __sincosf(ang, &sv, &cv);
        tsr[r][mi] = cv; tsi[r][mi] = sv;
      }
    }
    __syncthreads();
#pragma unroll 4
    for (int k = 0; k < kn; ++k) {
      float4 xv = *(const float4*)&xs_[k][cg_ * 4];
      float4 tr4 = *(const float4*)&tsr[k][mg * 4];
      float4 ti4 = *(const float4*)&tsi[k][mg * 4];
      float xv4[4] = {xv.x, xv.y, xv.z, xv.w};
      float trv[4] = {tr4.x, tr4.y, tr4.z, tr4.w};
      float tiv[4] = {ti4.x, ti4.y, ti4.z, ti4.w};
#pragma unroll
      for (int j = 0; j < 4; ++j)
#pragma unroll
        for (int q = 0; q < 4; ++q) {
          accr[j][q] = fmaf(xv4[q], trv[j], accr[j][q]);
          acci[j][q] = fmaf(xv4[q], tiv[j], acci[j][q]);
        }
    }
  }
#pragma unroll
  for (int j = 0; j < 4; ++j) {
    int gmm = mh * 64 + mg * 4 + j;
    if (gmm > 126) continue;
    size_t ob = ((size_t)t * 127 + gmm) * 64 + cg_ * 4;
    *(float4*)(ore + ob) = make_float4(accr[j][0], accr[j][1], accr[j][2], accr[j][3]);
    *(float4*)(oim + ob) = make_float4(acci[j][0], acci[j][1], acci[j][2], acci[j][3]);
  }
}

// ---------------- forward projection, planar, t-split over th ----------------
// grid (mm=127, lh=2, th=2), block 256.
__global__ __launch_bounds__(256) void ct_projf(const float* __restrict__ Deff,
                                                const float* __restrict__ fAre,
                                                const float* __restrict__ fAim,
                                                const float* __restrict__ fBre,
                                                const float* __restrict__ fBim,
                                                float* __restrict__ flmA_re, float* __restrict__ flmA_im,
                                                float* __restrict__ flmB_re, float* __restrict__ flmB_im) {
  __shared__ float Dsh[64][32];
  __shared__ float fr_[64][64], fi_[64][64];
  int mm = blockIdx.x, lh = blockIdx.y, th = blockIdx.z;
  float* ore = th ? flmB_re : flmA_re;
  float* oim = th ? flmB_im : flmA_im;
  int tb = th * 64;
  int tid = threadIdx.x;
  int cg_ = tid & 15, lg = tid >> 4;
  for (int e = tid; e < 64 * 32; e += 256) {
    int r = e >> 5, li = e & 31;
    Dsh[r][li] = Deff[((size_t)(tb + r) * 127 + mm) * 64 + lh * 32 + li];
  }
  for (int e = tid; e < 64 * 64; e += 256) {
    int r = e >> 6, c = e & 63;
    size_t idx = ((size_t)(tb + r) * 127 + mm) * 64 + c;
    fr_[r][c] = fAre[idx] + fBre[idx];
    fi_[r][c] = fAim[idx] + fBim[idx];
  }
  __syncthreads();
  float ar[2][4], ai[2][4];
#pragma unroll
  for (int li = 0; li < 2; ++li)
#pragma unroll
    for (int q = 0; q < 4; ++q) { ar[li][q] = 0.f; ai[li][q] = 0.f; }
#pragma unroll 4
  for (int k = 0; k < 64; ++k) {
    float4 fr4 = *(const float4*)&fr_[k][cg_ * 4];
    float4 fi4 = *(const float4*)&fi_[k][cg_ * 4];
    float2 d2 = *(const float2*)&Dsh[k][lg * 2];
    float frv[4] = {fr4.x, fr4.y, fr4.z, fr4.w};
    float fiv[4] = {fi4.x, fi4.y, fi4.z, fi4.w};
    float dv[2] = {d2.x, d2.y};
#pragma unroll
    for (int li = 0; li < 2; ++li)
#pragma unroll
      for (int q = 0; q < 4; ++q) {
        ar[li][q] = fmaf(dv[li], frv[q], ar[li][q]);
        ai[li][q] = fmaf(dv[li], fiv[q], ai[li][q]);
      }
  }
#pragma unroll
  for (int li = 0; li < 2; ++li) {
    size_t row = ((size_t)mm * 64 + lh * 32 + lg * 2 + li) * 64 + cg_ * 4;
    *(float4*)(ore + row) = make_float4(ar[li][0], ar[li][1], ar[li][2], ar[li][3]);
    *(float4*)(oim + row) = make_float4(ai[li][0], ai[li][1], ai[li][2], ai[li][3]);
  }
}

// ---------------- fused channel mixes, planar, Sl inline ----------------
// grid (l=64, mh=2, oh=2), block 256.
__global__ __launch_bounds__(256) void ct_mix(const float* __restrict__ flmA_re,
                                              const float* __restrict__ flmA_im,
                                              const float* __restrict__ flmB_re,
                                              const float* __restrict__ flmB_im,
                                              const float2* __restrict__ A2,
                                              const float* __restrict__ Mm,
                                              const float* __restrict__ scb,
                                              const float* __restrict__ bias2,
                                              const float* __restrict__ Deff,
                                              float* __restrict__ s_re, float* __restrict__ s_im,
                                              float* __restrict__ h_re, float* __restrict__ h_im) {
  __shared__ float Ar_[64][32], Ai_[64][32], Msh[64][32];
  __shared__ float Br_[64][65], Bi_[64][65];
  __shared__ float rb[256];
  int l = blockIdx.x, mh = blockIdx.y, oh = blockIdx.z;
  int tid = threadIdx.x;
  int og = tid & 15, mg = tid >> 4;
  // Sl[l] = sum_t Deff[t][63][l] (only needed when this block covers mm==63)
  rb[tid] = (mh == 0 && tid < 128) ? Deff[((size_t)tid * 127 + 63) * 64 + l] : 0.f;
  __syncthreads();
  for (int s = 128; s > 0; s >>= 1) {
    if (tid < s) rb[tid] += rb[tid + s];
    __syncthreads();
  }
  float slv = rb[0];
  for (int e = tid; e < 64 * 32; e += 256) {
    int r = e >> 5, oi = e & 31;
    float2 aa = A2[((size_t)l * 64 + r) * 64 + oh * 32 + oi];
    Ar_[r][oi] = aa.x; Ai_[r][oi] = aa.y;
    Msh[r][oi] = Mm[r * 64 + oh * 32 + oi];
  }
  for (int e = tid; e < 64 * 64; e += 256) {
    int mi = e >> 6, i = e & 63;
    int gmm = mh * 64 + mi; if (gmm > 126) gmm = 126;
    size_t idx = ((size_t)gmm * 64 + l) * 64 + i;
    Br_[mi][i] = flmA_re[idx] + flmB_re[idx];
    Bi_[mi][i] = flmA_im[idx] + flmB_im[idx];
  }
  __syncthreads();
  int o0 = oh * 32 + og * 2;
  float b0[2] = {scb[o0], scb[o0 + 1]};
  float sr[4][2], si[4][2], hr[4][2], hi[4][2];
#pragma unroll
  for (int jm = 0; jm < 4; ++jm)
#pragma unroll
    for (int qo = 0; qo < 2; ++qo) {
      sr[jm][qo] = b0[qo]; si[jm][qo] = 0.f; hr[jm][qo] = 0.f; hi[jm][qo] = 0.f;
    }
#pragma unroll 4
  for (int k = 0; k < 64; ++k) {
    float2 ar2 = *(const float2*)&Ar_[k][og * 2];
    float2 ai2 = *(const float2*)&Ai_[k][og * 2];
    float2 mv2 = *(const float2*)&Msh[k][og * 2];
    float br4[4], bi4[4];
#pragma unroll
    for (int jm = 0; jm < 4; ++jm) {
      br4[jm] = Br_[mg * 4 + jm][k];
      bi4[jm] = Bi_[mg * 4 + jm][k];
    }
    float arv[2] = {ar2.x, ar2.y}, aiv[2] = {ai2.x, ai2.y}, mvv[2] = {mv2.x, mv2.y};
#pragma unroll
    for (int jm = 0; jm < 4; ++jm)
#pragma unroll
      for (int qo = 0; qo < 2; ++qo) {
        sr[jm][qo] = fmaf(br4[jm], arv[qo], sr[jm][qo]);
        sr[jm][qo] = fmaf(-bi4[jm], aiv[qo], sr[jm][qo]);
        si[jm][qo] = fmaf(br4[jm], aiv[qo], si[jm][qo]);
        si[jm][qo] = fmaf(bi4[jm], arv[qo], si[jm][qo]);
        hr[jm][qo] = fmaf(br4[jm], mvv[qo], hr[jm][qo]);
        hi[jm][qo] = fmaf(bi4[jm], mvv[qo], hi[jm][qo]);
      }
  }
  float bb[2] = {bias2[o0], bias2[o0 + 1]};
#pragma unroll
  for (int jm = 0; jm < 4; ++jm) {
    int gmm = mh * 64 + mg * 4 + jm;
    if (gmm > 126) continue;
    if (gmm == 63) {
#pragma unroll
      for (int qo = 0; qo < 2; ++qo)
        hr[jm][qo] = fmaf(255.0f * slv, bb[qo], hr[jm][qo]);
    }
    size_t row = ((size_t)gmm * 64 + l) * 64 + o0;
    *(float2*)(s_re + row) = make_float2(sr[jm][0], sr[jm][1]);
    *(float2*)(s_im + row) = make_float2(si[jm][0], si[jm][1]);
    *(float2*)(h_re + row) = make_float2(hr[jm][0], hr[jm][1]);
    *(float2*)(h_im + row) = make_float2(hi[jm][0], hi[jm][1]);
  }
}

// ---------------- inverse projection, planar, c-split ----------------
// grid (mm=127, br=2, ch=2), block 256.
__global__ __launch_bounds__(256) void ct_proji(const float* __restrict__ Dinv,
                                                const float* __restrict__ s_re,
                                                const float* __restrict__ s_im,
                                                const float* __restrict__ h_re,
                                                const float* __restrict__ h_im,
                                                float* __restrict__ fos_re, float* __restrict__ fos_im,
                                                float* __restrict__ foh_re, float* __restrict__ foh_im) {
  __shared__ float Dsh[64][64];
  __shared__ float Br_[64][32], Bi_[64][32];
  int mm = blockIdx.x, br = blockIdx.y, ch = blockIdx.z;
  const float* ire = br ? h_re : s_re;
  const float* iim = br ? h_im : s_im;
  float* ore = br ? foh_re : fos_re;
  float* oim = br ? foh_im : fos_im;
  int tid = threadIdx.x;
  int cg_ = tid & 15, tg = tid >> 4;
  for (int e = tid; e < 64 * 64; e += 256) {
    int r = e >> 6, tt = e & 63;
    Dsh[r][tt] = Dinv[((size_t)mm * 64 + r) * 64 + tt];
  }
  for (int e = tid; e < 64 * 32; e += 256) {
    int r = e >> 5, cc = e & 31;
    size_t idx = ((size_t)mm * 64 + r) * 64 + ch * 32 + cc;
    Br_[r][cc] = ire[idx];
    Bi_[r][cc] = iim[idx];
  }
  __syncthreads();
  float ar[4][2], ai[4][2];
#pragma unroll
  for (int j = 0; j < 4; ++j)
#pragma unroll
    for (int q = 0; q < 2; ++q) { ar[j][q] = 0.f; ai[j][q] = 0.f; }
#pragma unroll 4
  for (int k = 0; k < 64; ++k) {
    float4 d4 = *(const float4*)&Dsh[k][tg * 4];
    float2 fr2 = *(const float2*)&Br_[k][cg_ * 2];
    float2 fi2 = *(const float2*)&Bi_[k][cg_ * 2];
    float dv[4] = {d4.x, d4.y, d4.z, d4.w};
    float frv[2] = {fr2.x, fr2.y}, fiv[2] = {fi2.x, fi2.y};
#pragma unroll
    for (int j = 0; j < 4; ++j)
#pragma unroll
      for (int q = 0; q < 2; ++q) {
        ar[j][q] = fmaf(dv[j], frv[q], ar[j][q]);
        ai[j][q] = fmaf(dv[j], fiv[q], ai[j][q]);
      }
  }
#pragma unroll
  for (int j = 0; j < 4; ++j) {
    int t = tg * 4 + j;
    size_t ob = ((size_t)t * 127 + mm) * 64 + ch * 32 + cg_ * 2;
    *(float2*)(ore + ob) = make_float2(ar[j][0], ar[j][1]);
    *(float2*)(oim + ob) = make_float2(ai[j][0], ai[j][1]);
  }
}

// ---------------- inverse DFT: tiled GEMM, inline twiddles, K(mm)-split ----------------
// grid (t=64, br=2, z=4: ph=z>>1, kh=z&1), block 256. Partial sums -> {x,h}sb{A,B}.
__global__ __launch_bounds__(256) void ct_idft(const float* __restrict__ fos_re,
                                               const float* __restrict__ fos_im,
                                               const float* __restrict__ foh_re,
                                               const float* __restrict__ foh_im,
                                               float* __restrict__ xsbA, float* __restrict__ xsbB,
                                               float* __restrict__ hsbA, float* __restrict__ hsbB) {
  __shared__ float Ar_[32][64], Ai_[32][64], Br_[32][64], Bi_[32][64];
  int t = blockIdx.x, br = blockIdx.y;
  int z = blockIdx.z;
  int ph = z >> 1, kh = z & 1;
  const float* fre = br ? foh_re : fos_re;
  const float* fim = br ? foh_im : fos_im;
  float* outp = br ? (kh ? hsbB : hsbA) : (kh ? xsbB : xsbA);
  int kbase = kh * 64;
  int Ktot = kh ? 63 : 64;
  int tid = threadIdx.x;
  int cg_ = tid & 15, pg = tid >> 4;
  float acc[4][4];
#pragma unroll
  for (int j = 0; j < 4; ++j)
#pragma unroll
    for (int q = 0; q < 4; ++q) acc[j][q] = 0.f;
  for (int k0 = 0; k0 < Ktot; k0 += 32) {
    int kn = (Ktot - k0 < 32) ? Ktot - k0 : 32;
    __syncthreads();
    for (int e = tid; e < 32 * 64; e += 256) {
      int r = e >> 6, j = e & 63;
      if (r < kn) {
        int gmm = kbase + k0 + r;
        int gp = ph * 64 + j; if (gp > 126) gp = 126;
        float ang = CN127F * (float)((gmm - 63) * gp);
        float sv, cv;
        __sincosf(ang, &sv, &cv);
        Ar_[r][j] = cv; Ai_[r][j] = sv;
        size_t bidx = ((size_t)t * 127 + gmm) * 64 + j;
        Br_[r][j] = fre[bidx]; Bi_[r][j] = fim[bidx];
      }
    }
    __syncthreads();
#pragma unroll 4
    for (int k = 0; k < kn; ++k) {
      float4 a_r = *(const float4*)&Ar_[k][pg * 4];
      float4 a_i = *(const float4*)&Ai_[k][pg * 4];
      float4 b_r = *(const float4*)&Br_[k][cg_ * 4];
      float4 b_i = *(const float4*)&Bi_[k][cg_ * 4];
      float arv[4] = {a_r.x, a_r.y, a_r.z, a_r.w};
      float aiv[4] = {a_i.x, a_i.y, a_i.z, a_i.w};
      float brv[4] = {b_r.x, b_r.y, b_r.z, b_r.w};
      float biv[4] = {b_i.x, b_i.y, b_i.z, b_i.w};
#pragma unroll
      for (int j = 0; j < 4; ++j)
#pragma unroll
        for (int q = 0; q < 4; ++q) {
          acc[j][q] = fmaf(brv[q], arv[j], acc[j][q]);
          acc[j][q] = fmaf(biv[q], -aiv[j], acc[j][q]);
        }
    }
  }
#pragma unroll
  for (int j = 0; j < 4; ++j) {
    int gp = ph * 64 + pg * 4 + j;
    if (gp > 126) continue;
    *(float4*)(outp + ((size_t)t * 127 + gp) * 64 + cg_ * 4) =
        make_float4(acc[j][0], acc[j][1], acc[j][2], acc[j][3]);
  }
}

// ---------------- epilogue: one wave per row ----------------
// grid 2032, block 256 (4 waves).
__global__ __launch_bounds__(256) void ct_fin(const float* __restrict__ xsbA,
                                              const float* __restrict__ xsbB,
                                              const float* __restrict__ hsbA,
                                              const float* __restrict__ hsbB,
                                              const float* __restrict__ c2w,
                                              const float* __restrict__ c2b,
                                              const float* __restrict__ tv,
                                              const float* __restrict__ lns,
                                              const float* __restrict__ lnb,
                                              float* __restrict__ out) {
  int w = threadIdx.x >> 6, lane = threadIdx.x & 63;
  size_t row = (size_t)blockIdx.x * 4 + w;  // < 8128
  size_t base = row * 64 + lane;
  float hv = hsbA[base] + hsbB[base];
  float xv = xsbA[base] + xsbB[base];
  float acc = c2b[lane] + tv[64 + lane];
#pragma unroll 16
  for (int i = 0; i < 64; ++i)
    acc = fmaf(__shfl(hv, i, 64), c2w[i * 64 + lane], acc);
  float ss = wave_sum64(xv * xv);
  xv = xv / (sqrtf(ss) + 1e-6f);
  float y = xv + acc;
  float g = gelu_tanh(y);
  float mu = wave_sum64(g) * (1.0f / 64.0f);
  float d = g - mu;
  float var = wave_sum64(d * d) * (1.0f / 64.0f);
  out[base] = d * rsqrtf(var + 1e-6f) * lns[lane] + lnb[lane];
}

// ---------------- host launcher ----------------
extern "C" void kernel_launch(void* const* d_in, const int* in_sizes, int n_in,
                              void* d_out, int out_size, void* d_ws, size_t ws_size,
                              hipStream_t stream) {
  const float* x = (const float*)d_in[0];
  const float* temb = (const float*)d_in[1];
  const float* scw = (const float*)d_in[2];
  const float* scb = (const float*)d_in[3];
  const float* swr = (const float*)d_in[4];
  const float* swi = (const float*)d_in[5];
  const float* strw = (const float*)d_in[6];
  const float* strb = (const float*)d_in[7];
  const float* stiw = (const float*)d_in[8];
  const float* stib = (const float*)d_in[9];
  const float* c1w = (const float*)d_in[10];
  const float* c1b = (const float*)d_in[11];
  const float* stw = (const float*)d_in[12];
  const float* stb = (const float*)d_in[13];
  const float* sweight = (const float*)d_in[14];
  const float* c2w = (const float*)d_in[15];
  const float* c2b = (const float*)d_in[16];
  const float* lns = (const float*)d_in[17];
  const float* lnb = (const float*)d_in[18];
  float* out = (float*)d_out;

  char* base = (char*)d_ws;
  size_t off = 0;
  auto alloc = [&](size_t bytes) -> void* {
    void* p = base + off;
    off += (bytes + 255) & ~(size_t)255;
    return p;
  };
  float* tv = (float*)alloc(128 * sizeof(float));
  float* Mm = (float*)alloc(4096 * sizeof(float));
  float* bias2 = (float*)alloc(64 * sizeof(float));
  float2* A2 = (float2*)alloc(262144 * sizeof(float2));
  float* Deff = (float*)alloc(1040384 * sizeof(float));   // [t<128][mm][l]
  float* Dinv = (float*)alloc(520192 * sizeof(float));    // [mm][l][t<64]
  float* ftmA_re = (float*)alloc(1040384 * sizeof(float));
  float* ftmA_im = (float*)alloc(1040384 * sizeof(float));
  float* ftmB_re = (float*)alloc(1040384 * sizeof(float));
  float* ftmB_im = (float*)alloc(1040384 * sizeof(float));
  float* flmA_re = (float*)alloc(520192 * sizeof(float));
  float* flmA_im = (float*)alloc(520192 * sizeof(float));
  float* flmB_re = (float*)alloc(520192 * sizeof(float));
  float* flmB_im = (float*)alloc(520192 * sizeof(float));
  if (off > ws_size) return;  // workspace too small -> visible failure
  // aliases with stage-disjoint lifetimes:
  float* s_re = ftmA_re;          // mix outputs (ftm consumed by projf)
  float* s_im = ftmA_im;
  float* h_re = ftmB_re;
  float* h_im = ftmB_im;
  float* fos_re = Deff;           // proji outputs (Deff consumed by projf/mix)
  float* fos_im = Deff + 520192;
  float* foh_re = flmA_re;        // (flmA consumed by mix)
  float* foh_im = flmA_im;
  float* xsbA = flmB_re;          // idft outputs (flmB consumed by mix)
  float* xsbB = flmB_im;
  float* hsbA = ftmA_re;          // (s consumed by proji)
  float* hsbB = ftmA_im;

  hipLaunchKernelGGL(ct_setup, dim3(384), dim3(256), 0, stream, Deff, Dinv,
                     temb, strw, strb, stiw, stib, stw, stb,
                     scw, swr, swi, c1w, c1b, sweight, A2, Mm, bias2, tv);
  hipLaunchKernelGGL(ct_dft, dim3(128, 2, 2), dim3(256), 0, stream, x,
                     ftmA_re, ftmA_im, ftmB_re, ftmB_im);
  hipLaunchKernelGGL(ct_projf, dim3(127, 2, 2), dim3(256), 0, stream, Deff,
                     ftmA_re, ftmA_im, ftmB_re, ftmB_im,
                     flmA_re, flmA_im, flmB_re, flmB_im);
  hipLaunchKernelGGL(ct_mix, dim3(64, 2, 2), dim3(256), 0, stream,
                     flmA_re, flmA_im, flmB_re, flmB_im, A2, Mm, scb, bias2, Deff,
                     s_re, s_im, h_re, h_im);
  hipLaunchKernelGGL(ct_proji, dim3(127, 2, 2), dim3(256), 0, stream, Dinv,
                     s_re, s_im, h_re, h_im, fos_re, fos_im, foh_re, foh_im);
  hipLaunchKernelGGL(ct_idft, dim3(64, 2, 4), dim3(256), 0, stream,
                     fos_re, fos_im, foh_re, foh_im, xsbA, xsbB, hsbA, hsbB);
  hipLaunchKernelGGL(ct_fin, dim3(2032), dim3(256), 0, stream, xsbA, xsbB, hsbA, hsbB,
                     c2w, c2b, tv, lns, lnb, out);
}

// Round 10
// 202.902 us; speedup vs baseline: 2.6845x; 1.0446x over previous
//
#include <hip/hip_runtime.h>
#include <math.h>

#define DPI 3.141592653589793238462643383279502884

// ---------------- device helpers ----------------
__device__ __forceinline__ float wave_sum64(float v) {
#pragma unroll
  for (int off = 32; off > 0; off >>= 1) v += __shfl_xor(v, off, 64);
  return v;
}

__device__ __forceinline__ float gelu_tanh(float v) {
  float u = 0.7978845608028654f * (v + 0.044715f * v * v * v);
  return 0.5f * v * (1.0f + tanhf(u));
}

#define CN255F ((float)(-2.0 * DPI / 255.0))
#define CN127F ((float)(2.0 * DPI / 127.0))

// ======================= ct_pre: dft GEMM + all setup, one launch =======================
// blocks 0..511   : forward DFT tiles (t=vb>>2, mh=(vb>>1)&1, ph=vb&1)
// blocks 512..766 : Wigner tables (wb=vb-512: wb<128 -> Deff[t=wb], else Dinv[mm=wb-128])
// blocks 767..830 : A2[l][i][o] (l=vb-767)
// blocks 831..894 : Mm[j][o] (+bias2 at j==0)
// block  895      : tv[128]
// No inter-block dependencies: dft reads x only; setup reads weights only.

__device__ __forceinline__ void dft_block(int idx, int tid, const float* __restrict__ x,
                                          float* __restrict__ Are, float* __restrict__ Aim,
                                          float* __restrict__ Bre, float* __restrict__ Bim,
                                          char* sm) {
  float* xs_ = (float*)sm;             // [64][64]
  float* tsr = (float*)(sm + 16384);   // [64][64]
  float* tsi = (float*)(sm + 32768);   // [64][64]
  int t = idx >> 2, mh = (idx >> 1) & 1, ph = idx & 1;
  float* ore = ph ? Bre : Are;
  float* oim = ph ? Bim : Aim;
  int pbase = ph * 128;
  int Ktot = ph ? 127 : 128;
  int cg_ = tid & 15, mg = tid >> 4;
  float accr[4][4], acci[4][4];
#pragma unroll
  for (int j = 0; j < 4; ++j)
#pragma unroll
    for (int q = 0; q < 4; ++q) { accr[j][q] = 0.f; acci[j][q] = 0.f; }
  for (int k0 = 0; k0 < Ktot; k0 += 64) {
    int kn = (Ktot - k0 < 64) ? Ktot - k0 : 64;
    __syncthreads();
    {
      int r = tid >> 2, c4 = (tid & 3) * 16;
      if (r < kn) {
        const float4* src = (const float4*)(x + ((size_t)t * 255 + pbase + k0 + r) * 64 + c4);
        float4* dst = (float4*)&xs_[r * 64 + c4];
        dst[0] = src[0]; dst[1] = src[1]; dst[2] = src[2]; dst[3] = src[3];
      }
    }
    for (int e = tid; e < 64 * 64; e += 256) {
      int r = e >> 6, mi = e & 63;
      if (r < kn) {
        int gcol = mh * 64 + mi; if (gcol > 126) gcol = 126;
        int p = pbase + k0 + r;
        float ang = CN255F * (float)((gcol - 63) * p);
        float sv, cv;
        __sincosf(ang, &sv, &cv);
        tsr[r * 64 + mi] = cv; tsi[r * 64 + mi] = sv;
      }
    }
    __syncthreads();
#pragma unroll 4
    for (int k = 0; k < kn; ++k) {
      float4 xv = *(const float4*)&xs_[k * 64 + cg_ * 4];
      float4 tr4 = *(const float4*)&tsr[k * 64 + mg * 4];
      float4 ti4 = *(const float4*)&tsi[k * 64 + mg * 4];
      float xv4[4] = {xv.x, xv.y, xv.z, xv.w};
      float trv[4] = {tr4.x, tr4.y, tr4.z, tr4.w};
      float tiv[4] = {ti4.x, ti4.y, ti4.z, ti4.w};
#pragma unroll
      for (int j = 0; j < 4; ++j)
#pragma unroll
        for (int q = 0; q < 4; ++q) {
          accr[j][q] = fmaf(xv4[q], trv[j], accr[j][q]);
          acci[j][q] = fmaf(xv4[q], tiv[j], acci[j][q]);
        }
    }
  }
#pragma unroll
  for (int j = 0; j < 4; ++j) {
    int gmm = mh * 64 + mg * 4 + j;
    if (gmm > 126) continue;
    size_t ob = ((size_t)t * 127 + gmm) * 64 + cg_ * 4;
    *(float4*)(ore + ob) = make_float4(accr[j][0], accr[j][1], accr[j][2], accr[j][3]);
    *(float4*)(oim + ob) = make_float4(acci[j][0], acci[j][1], acci[j][2], acci[j][3]);
  }
}

__device__ __forceinline__ void wigner_block(int wb, int tid, float* __restrict__ Deff,
                                             float* __restrict__ Dinv, char* sm) {
  float* LF = (float*)sm;             // [128] log(n!)
  double* red = (double*)(sm + 512);  // [64]
  float* clf = (float*)(sm + 1024);   // [64]
  int mode = (wb < 128) ? 0 : 1;
  int t, mm;
  if (mode == 0) { t = wb; mm = tid; }
  else { mm = wb - 128; t = (tid < 64) ? tid : 63; }
  // log-factorial table via parallel prefix scan (fp32; |err| ~1e-5 in exponent)
  if (tid < 64) clf[tid] = (float)(-sqrt((2.0 * tid + 1.0) / (4.0 * DPI)));
  if (tid < 128) LF[tid] = (tid == 0) ? 0.f : logf((float)tid);
  __syncthreads();
  for (int s = 1; s < 128; s <<= 1) {
    float add = (tid < 128 && tid >= s) ? LF[tid - s] : 0.f;
    __syncthreads();
    if (tid < 128) LF[tid] += add;
    __syncthreads();
  }
  double denomN = (mode == 0) ? 255.0 : 127.0;
  double beta = (2.0 * t + 1.0) * DPI / denomN;
  float coeff = 1.0f;
  if (mode == 0) {
    // quad-weight pair sum (wq[t]+wq[254-t]) lane-parallel
    if (tid < 63) {
      int k = 2 * (tid + 1);
      red[tid] = 8.0 * cos((double)k * beta) / (1.0 - (double)k * (double)k);
    } else if (tid == 63) {
      red[63] = 4.0;
    }
    __syncthreads();
    for (int s = 32; s > 0; s >>= 1) {
      if (tid < s) red[tid] += red[tid + s];
      __syncthreads();
    }
    double s = red[0] / 255.0;
    if (t == 127) s *= 0.5;
    coeff = (float)(s * (2.0 * DPI / 255.0));
  }
  bool active = (mode == 0) ? (tid < 127) : (tid < 64);
  if (!active) return;  // all barriers above
  int m = mm - 63;
  double chd, shd;
  sincos(0.5 * beta, &shd, &chd);
  float cbf = (float)cos(beta);
  float chf = (float)chd, shf = (float)shd;
  int am = (m < 0) ? -m : m;
  int l0v = (am > 1) ? am : 1;
  float seed;
  if (m == 0) {
    seed = -1.4142135623730951f * shf * chf;
  } else {
    int j = am;
    float lch = logf(chf), lsh = logf(shf);
    float e0 = 0.5f * (LF[2 * j] - LF[j - 1] - LF[j + 1]);
    float expo = (m >= 1) ? e0 + (float)(j - 1) * lch + (float)(j + 1) * lsh
                          : e0 + (float)(j + 1) * lch + (float)(j - 1) * lsh;
    float sv = __expf(expo);
    seed = (m >= 1 && ((m + 1) & 1)) ? -sv : sv;
  }
  // fp32 upward recurrence (stable: dominant-solution direction)
  float dl = seed, dm1 = 0.0f, S_cur = 0.0f;
  float mf = (float)m;
  for (int l = 0; l < 64; ++l) {
    float val = 0.0f;
    if (l >= l0v) {
      val = dl * coeff * clf[l];
      float Ld = (float)l, lp = Ld + 1.0f;
      float S_next = sqrtf((lp * lp - mf * mf) * (lp * lp - 1.0f));
      float num1 = (2.0f * Ld + 1.0f) * (Ld * lp * cbf + mf);
      float dn = (num1 * dl - lp * S_cur * dm1) / (Ld * S_next);
      dm1 = dl; dl = dn; S_cur = S_next;
    }
    if (mode == 0) Deff[((size_t)t * 127 + mm) * 64 + l] = val;
    else Dinv[((size_t)mm * 64 + l) * 64 + t] = val;
  }
}

__device__ __forceinline__ void a2_block(int l, int tid, const float* __restrict__ temb,
                                         const float* __restrict__ trw, const float* __restrict__ trb,
                                         const float* __restrict__ tiw, const float* __restrict__ tib,
                                         const float* __restrict__ scw, const float* __restrict__ swr,
                                         const float* __restrict__ swi, float2* __restrict__ A2,
                                         char* sm) {
  float* fb1 = (float*)sm;
  float* fb2 = (float*)(sm + 1024);
  fb1[tid] = temb[tid] * trw[tid * 64 + l];
  fb2[tid] = temb[tid] * tiw[tid * 64 + l];
  __syncthreads();
  for (int s = 128; s > 0; s >>= 1) {
    if (tid < s) { fb1[tid] += fb1[tid + s]; fb2[tid] += fb2[tid + s]; }
    __syncthreads();
  }
  float tr = fb1[0] + trb[l], ti = fb2[0] + tib[l];
  int o = tid & 63, iq = tid >> 6;
  for (int i = iq * 16; i < iq * 16 + 16; ++i) {
    int idx = (l * 64 + i) * 64 + o;
    float r = swr[idx], s2 = swi[idx];
    A2[idx] = make_float2(scw[i * 64 + o] + tr * r - ti * s2, tr * s2 + ti * r);
  }
}

__device__ __forceinline__ void m_block(int j, int tid, const float* __restrict__ temb,
                                        const float* __restrict__ stw, const float* __restrict__ stb,
                                        const float* __restrict__ c1w, const float* __restrict__ c1b,
                                        const float* __restrict__ sweight, float* __restrict__ Mm,
                                        float* __restrict__ bias2, char* sm) {
  float* fb1 = (float*)sm;
  float* fb2 = (float*)(sm + 1024);
  int o = tid & 63, part = tid >> 6;
  float p = 0.f;
  for (int k = part * 64; k < part * 64 + 64; ++k)
    p = fmaf(temb[k], stw[k * 128 + o], p);
  fb1[part * 64 + o] = p;
  __syncthreads();
  if (part == 0) fb2[o] = fb1[o] + fb1[64 + o] + fb1[128 + o] + fb1[192 + o] + stb[o];
  __syncthreads();
  float tvo = fb2[o];
  float q = 0.f;
  for (int i = part * 16; i < part * 16 + 16; ++i)
    q = fmaf(c1w[j * 64 + i], sweight[i * 64 + o], q);
  __syncthreads();
  fb1[part * 64 + o] = q;
  __syncthreads();
  if (part == 0) Mm[j * 64 + o] = tvo * (fb1[o] + fb1[64 + o] + fb1[128 + o] + fb1[192 + o]);
  if (j == 0) {
    float bq = 0.f;
    for (int i = part * 16; i < part * 16 + 16; ++i)
      bq = fmaf(c1b[i], sweight[i * 64 + o], bq);
    __syncthreads();
    fb1[part * 64 + o] = bq;
    __syncthreads();
    if (part == 0) bias2[o] = tvo * (fb1[o] + fb1[64 + o] + fb1[128 + o] + fb1[192 + o]);
  }
}

__device__ __forceinline__ void tv_block(int tid, const float* __restrict__ temb,
                                         const float* __restrict__ stw, const float* __restrict__ stb,
                                         float* __restrict__ tv, char* sm) {
  float* fb1 = (float*)sm;
  int o = tid & 127, part = tid >> 7;
  float p = 0.f;
  for (int k = part * 128; k < part * 128 + 128; ++k)
    p = fmaf(temb[k], stw[k * 128 + o], p);
  fb1[part * 128 + o] = p;
  __syncthreads();
  if (part == 0) tv[o] = fb1[o] + fb1[128 + o] + stb[o];
}

__global__ __launch_bounds__(256) void ct_pre(
    const float* __restrict__ x, const float* __restrict__ temb,
    const float* __restrict__ trw, const float* __restrict__ trb,
    const float* __restrict__ tiw, const float* __restrict__ tib,
    const float* __restrict__ stw, const float* __restrict__ stb,
    const float* __restrict__ scw, const float* __restrict__ swr,
    const float* __restrict__ swi, const float* __restrict__ c1w,
    const float* __restrict__ c1b, const float* __restrict__ sweight,
    float* __restrict__ Deff, float* __restrict__ Dinv,
    float2* __restrict__ A2, float* __restrict__ Mm,
    float* __restrict__ bias2, float* __restrict__ tv,
    float* __restrict__ ftmA_re, float* __restrict__ ftmA_im,
    float* __restrict__ ftmB_re, float* __restrict__ ftmB_im) {
  __shared__ __align__(16) char sm[49152];
  int vb = blockIdx.x;
  int tid = threadIdx.x;
  if (vb < 512) dft_block(vb, tid, x, ftmA_re, ftmA_im, ftmB_re, ftmB_im, sm);
  else if (vb < 767) wigner_block(vb - 512, tid, Deff, Dinv, sm);
  else if (vb < 831) a2_block(vb - 767, tid, temb, trw, trb, tiw, tib, scw, swr, swi, A2, sm);
  else if (vb < 895) m_block(vb - 831, tid, temb, stw, stb, c1w, c1b, sweight, Mm, bias2, sm);
  else tv_block(tid, temb, stw, stb, tv, sm);
}

// ---------------- forward projection, planar, t-split over th ----------------
// grid (mm=127, lh=2, th=2), block 256.
__global__ __launch_bounds__(256) void ct_projf(const float* __restrict__ Deff,
                                                const float* __restrict__ fAre,
                                                const float* __restrict__ fAim,
                                                const float* __restrict__ fBre,
                                                const float* __restrict__ fBim,
                                                float* __restrict__ flmA_re, float* __restrict__ flmA_im,
                                                float* __restrict__ flmB_re, float* __restrict__ flmB_im) {
  __shared__ float Dsh[64][32];
  __shared__ float fr_[64][64], fi_[64][64];
  int mm = blockIdx.x, lh = blockIdx.y, th = blockIdx.z;
  float* ore = th ? flmB_re : flmA_re;
  float* oim = th ? flmB_im : flmA_im;
  int tb = th * 64;
  int tid = threadIdx.x;
  int cg_ = tid & 15, lg = tid >> 4;
  for (int e = tid; e < 64 * 32; e += 256) {
    int r = e >> 5, li = e & 31;
    Dsh[r][li] = Deff[((size_t)(tb + r) * 127 + mm) * 64 + lh * 32 + li];
  }
  for (int e = tid; e < 64 * 64; e += 256) {
    int r = e >> 6, c = e & 63;
    size_t idx = ((size_t)(tb + r) * 127 + mm) * 64 + c;
    fr_[r][c] = fAre[idx] + fBre[idx];
    fi_[r][c] = fAim[idx] + fBim[idx];
  }
  __syncthreads();
  float ar[2][4], ai[2][4];
#pragma unroll
  for (int li = 0; li < 2; ++li)
#pragma unroll
    for (int q = 0; q < 4; ++q) { ar[li][q] = 0.f; ai[li][q] = 0.f; }
#pragma unroll 4
  for (int k = 0; k < 64; ++k) {
    float4 fr4 = *(const float4*)&fr_[k][cg_ * 4];
    float4 fi4 = *(const float4*)&fi_[k][cg_ * 4];
    float2 d2 = *(const float2*)&Dsh[k][lg * 2];
    float frv[4] = {fr4.x, fr4.y, fr4.z, fr4.w};
    float fiv[4] = {fi4.x, fi4.y, fi4.z, fi4.w};
    float dv[2] = {d2.x, d2.y};
#pragma unroll
    for (int li = 0; li < 2; ++li)
#pragma unroll
      for (int q = 0; q < 4; ++q) {
        ar[li][q] = fmaf(dv[li], frv[q], ar[li][q]);
        ai[li][q] = fmaf(dv[li], fiv[q], ai[li][q]);
      }
  }
#pragma unroll
  for (int li = 0; li < 2; ++li) {
    size_t row = ((size_t)mm * 64 + lh * 32 + lg * 2 + li) * 64 + cg_ * 4;
    *(float4*)(ore + row) = make_float4(ar[li][0], ar[li][1], ar[li][2], ar[li][3]);
    *(float4*)(oim + row) = make_float4(ai[li][0], ai[li][1], ai[li][2], ai[li][3]);
  }
}

// ---------------- fused channel mixes, planar, Sl inline ----------------
// grid (l=64, mh=2, oh=2), block 256.
__global__ __launch_bounds__(256) void ct_mix(const float* __restrict__ flmA_re,
                                              const float* __restrict__ flmA_im,
                                              const float* __restrict__ flmB_re,
                                              const float* __restrict__ flmB_im,
                                              const float2* __restrict__ A2,
                                              const float* __restrict__ Mm,
                                              const float* __restrict__ scb,
                                              const float* __restrict__ bias2,
                                              const float* __restrict__ Deff,
                                              float* __restrict__ s_re, float* __restrict__ s_im,
                                              float* __restrict__ h_re, float* __restrict__ h_im) {
  __shared__ float Ar_[64][32], Ai_[64][32], Msh[64][32];
  __shared__ float Br_[64][65], Bi_[64][65];
  __shared__ float rb[256];
  int l = blockIdx.x, mh = blockIdx.y, oh = blockIdx.z;
  int tid = threadIdx.x;
  int og = tid & 15, mg = tid >> 4;
  rb[tid] = (mh == 0 && tid < 128) ? Deff[((size_t)tid * 127 + 63) * 64 + l] : 0.f;
  __syncthreads();
  for (int s = 128; s > 0; s >>= 1) {
    if (tid < s) rb[tid] += rb[tid + s];
    __syncthreads();
  }
  float slv = rb[0];
  for (int e = tid; e < 64 * 32; e += 256) {
    int r = e >> 5, oi = e & 31;
    float2 aa = A2[((size_t)l * 64 + r) * 64 + oh * 32 + oi];
    Ar_[r][oi] = aa.x; Ai_[r][oi] = aa.y;
    Msh[r][oi] = Mm[r * 64 + oh * 32 + oi];
  }
  for (int e = tid; e < 64 * 64; e += 256) {
    int mi = e >> 6, i = e & 63;
    int gmm = mh * 64 + mi; if (gmm > 126) gmm = 126;
    size_t idx = ((size_t)gmm * 64 + l) * 64 + i;
    Br_[mi][i] = flmA_re[idx] + flmB_re[idx];
    Bi_[mi][i] = flmA_im[idx] + flmB_im[idx];
  }
  __syncthreads();
  int o0 = oh * 32 + og * 2;
  float b0[2] = {scb[o0], scb[o0 + 1]};
  float sr[4][2], si[4][2], hr[4][2], hi[4][2];
#pragma unroll
  for (int jm = 0; jm < 4; ++jm)
#pragma unroll
    for (int qo = 0; qo < 2; ++qo) {
      sr[jm][qo] = b0[qo]; si[jm][qo] = 0.f; hr[jm][qo] = 0.f; hi[jm][qo] = 0.f;
    }
#pragma unroll 4
  for (int k = 0; k < 64; ++k) {
    float2 ar2 = *(const float2*)&Ar_[k][og * 2];
    float2 ai2 = *(const float2*)&Ai_[k][og * 2];
    float2 mv2 = *(const float2*)&Msh[k][og * 2];
    float br4[4], bi4[4];
#pragma unroll
    for (int jm = 0; jm < 4; ++jm) {
      br4[jm] = Br_[mg * 4 + jm][k];
      bi4[jm] = Bi_[mg * 4 + jm][k];
    }
    float arv[2] = {ar2.x, ar2.y}, aiv[2] = {ai2.x, ai2.y}, mvv[2] = {mv2.x, mv2.y};
#pragma unroll
    for (int jm = 0; jm < 4; ++jm)
#pragma unroll
      for (int qo = 0; qo < 2; ++qo) {
        sr[jm][qo] = fmaf(br4[jm], arv[qo], sr[jm][qo]);
        sr[jm][qo] = fmaf(-bi4[jm], aiv[qo], sr[jm][qo]);
        si[jm][qo] = fmaf(br4[jm], aiv[qo], si[jm][qo]);
        si[jm][qo] = fmaf(bi4[jm], arv[qo], si[jm][qo]);
        hr[jm][qo] = fmaf(br4[jm], mvv[qo], hr[jm][qo]);
        hi[jm][qo] = fmaf(bi4[jm], mvv[qo], hi[jm][qo]);
      }
  }
  float bb[2] = {bias2[o0], bias2[o0 + 1]};
#pragma unroll
  for (int jm = 0; jm < 4; ++jm) {
    int gmm = mh * 64 + mg * 4 + jm;
    if (gmm > 126) continue;
    if (gmm == 63) {
#pragma unroll
      for (int qo = 0; qo < 2; ++qo)
        hr[jm][qo] = fmaf(255.0f * slv, bb[qo], hr[jm][qo]);
    }
    size_t row = ((size_t)gmm * 64 + l) * 64 + o0;
    *(float2*)(s_re + row) = make_float2(sr[jm][0], sr[jm][1]);
    *(float2*)(s_im + row) = make_float2(si[jm][0], si[jm][1]);
    *(float2*)(h_re + row) = make_float2(hr[jm][0], hr[jm][1]);
    *(float2*)(h_im + row) = make_float2(hi[jm][0], hi[jm][1]);
  }
}

// ---------------- inverse projection, planar, c-split ----------------
// grid (mm=127, br=2, ch=2), block 256.
__global__ __launch_bounds__(256) void ct_proji(const float* __restrict__ Dinv,
                                                const float* __restrict__ s_re,
                                                const float* __restrict__ s_im,
                                                const float* __restrict__ h_re,
                                                const float* __restrict__ h_im,
                                                float* __restrict__ fos_re, float* __restrict__ fos_im,
                                                float* __restrict__ foh_re, float* __restrict__ foh_im) {
  __shared__ float Dsh[64][64];
  __shared__ float Br_[64][32], Bi_[64][32];
  int mm = blockIdx.x, br = blockIdx.y, ch = blockIdx.z;
  const float* ire = br ? h_re : s_re;
  const float* iim = br ? h_im : s_im;
  float* ore = br ? foh_re : fos_re;
  float* oim = br ? foh_im : fos_im;
  int tid = threadIdx.x;
  int cg_ = tid & 15, tg = tid >> 4;
  for (int e = tid; e < 64 * 64; e += 256) {
    int r = e >> 6, tt = e & 63;
    Dsh[r][tt] = Dinv[((size_t)mm * 64 + r) * 64 + tt];
  }
  for (int e = tid; e < 64 * 32; e += 256) {
    int r = e >> 5, cc = e & 31;
    size_t idx = ((size_t)mm * 64 + r) * 64 + ch * 32 + cc;
    Br_[r][cc] = ire[idx];
    Bi_[r][cc] = iim[idx];
  }
  __syncthreads();
  float ar[4][2], ai[4][2];
#pragma unroll
  for (int j = 0; j < 4; ++j)
#pragma unroll
    for (int q = 0; q < 2; ++q) { ar[j][q] = 0.f; ai[j][q] = 0.f; }
#pragma unroll 4
  for (int k = 0; k < 64; ++k) {
    float4 d4 = *(const float4*)&Dsh[k][tg * 4];
    float2 fr2 = *(const float2*)&Br_[k][cg_ * 2];
    float2 fi2 = *(const float2*)&Bi_[k][cg_ * 2];
    float dv[4] = {d4.x, d4.y, d4.z, d4.w};
    float frv[2] = {fr2.x, fr2.y}, fiv[2] = {fi2.x, fi2.y};
#pragma unroll
    for (int j = 0; j < 4; ++j)
#pragma unroll
      for (int q = 0; q < 2; ++q) {
        ar[j][q] = fmaf(dv[j], frv[q], ar[j][q]);
        ai[j][q] = fmaf(dv[j], fiv[q], ai[j][q]);
      }
  }
#pragma unroll
  for (int j = 0; j < 4; ++j) {
    int t = tg * 4 + j;
    size_t ob = ((size_t)t * 127 + mm) * 64 + ch * 32 + cg_ * 2;
    *(float2*)(ore + ob) = make_float2(ar[j][0], ar[j][1]);
    *(float2*)(oim + ob) = make_float2(ai[j][0], ai[j][1]);
  }
}

// ---------------- inverse DFT: tiled GEMM, inline twiddles, K(mm)-split ----------------
// grid (t=64, br=2, z=4: ph=z>>1, kh=z&1), block 256. Partial sums -> {x,h}sb{A,B}.
__global__ __launch_bounds__(256) void ct_idft(const float* __restrict__ fos_re,
                                               const float* __restrict__ fos_im,
                                               const float* __restrict__ foh_re,
                                               const float* __restrict__ foh_im,
                                               float* __restrict__ xsbA, float* __restrict__ xsbB,
                                               float* __restrict__ hsbA, float* __restrict__ hsbB) {
  __shared__ float Ar_[32][64], Ai_[32][64], Br_[32][64], Bi_[32][64];
  int t = blockIdx.x, br = blockIdx.y;
  int z = blockIdx.z;
  int ph = z >> 1, kh = z & 1;
  const float* fre = br ? foh_re : fos_re;
  const float* fim = br ? foh_im : fos_im;
  float* outp = br ? (kh ? hsbB : hsbA) : (kh ? xsbB : xsbA);
  int kbase = kh * 64;
  int Ktot = kh ? 63 : 64;
  int tid = threadIdx.x;
  int cg_ = tid & 15, pg = tid >> 4;
  float acc[4][4];
#pragma unroll
  for (int j = 0; j < 4; ++j)
#pragma unroll
    for (int q = 0; q < 4; ++q) acc[j][q] = 0.f;
  for (int k0 = 0; k0 < Ktot; k0 += 32) {
    int kn = (Ktot - k0 < 32) ? Ktot - k0 : 32;
    __syncthreads();
    for (int e = tid; e < 32 * 64; e += 256) {
      int r = e >> 6, j = e & 63;
      if (r < kn) {
        int gmm = kbase + k0 + r;
        int gp = ph * 64 + j; if (gp > 126) gp = 126;
        float ang = CN127F * (float)((gmm - 63) * gp);
        float sv, cv;
        __sincosf(ang, &sv, &cv);
        Ar_[r][j] = cv; Ai_[r][j] = sv;
        size_t bidx = ((size_t)t * 127 + gmm) * 64 + j;
        Br_[r][j] = fre[bidx]; Bi_[r][j] = fim[bidx];
      }
    }
    __syncthreads();
#pragma unroll 4
    for (int k = 0; k < kn; ++k) {
      float4 a_r = *(const float4*)&Ar_[k][pg * 4];
      float4 a_i = *(const float4*)&Ai_[k][pg * 4];
      float4 b_r = *(const float4*)&Br_[k][cg_ * 4];
      float4 b_i = *(const float4*)&Bi_[k][cg_ * 4];
      float arv[4] = {a_r.x, a_r.y, a_r.z, a_r.w};
      float aiv[4] = {a_i.x, a_i.y, a_i.z, a_i.w};
      float brv[4] = {b_r.x, b_r.y, b_r.z, b_r.w};
      float biv[4] = {b_i.x, b_i.y, b_i.z, b_i.w};
#pragma unroll
      for (int j = 0; j < 4; ++j)
#pragma unroll
        for (int q = 0; q < 4; ++q) {
          acc[j][q] = fmaf(brv[q], arv[j], acc[j][q]);
          acc[j][q] = fmaf(biv[q], -aiv[j], acc[j][q]);
        }
    }
  }
#pragma unroll
  for (int j = 0; j < 4; ++j) {
    int gp = ph * 64 + pg * 4 + j;
    if (gp > 126) continue;
    *(float4*)(outp + ((size_t)t * 127 + gp) * 64 + cg_ * 4) =
        make_float4(acc[j][0], acc[j][1], acc[j][2], acc[j][3]);
  }
}

// ---------------- epilogue: one wave per row ----------------
// grid 2032, block 256 (4 waves).
__global__ __launch_bounds__(256) void ct_fin(const float* __restrict__ xsbA,
                                              const float* __restrict__ xsbB,
                                              const float* __restrict__ hsbA,
                                              const float* __restrict__ hsbB,
                                              const float* __restrict__ c2w,
                                              const float* __restrict__ c2b,
                                              const float* __restrict__ tv,
                                              const float* __restrict__ lns,
                                              const float* __restrict__ lnb,
                                              float* __restrict__ out) {
  int w = threadIdx.x >> 6, lane = threadIdx.x & 63;
  size_t row = (size_t)blockIdx.x * 4 + w;  // < 8128
  size_t base = row * 64 + lane;
  float hv = hsbA[base] + hsbB[base];
  float xv = xsbA[base] + xsbB[base];
  float acc = c2b[lane] + tv[64 + lane];
#pragma unroll 16
  for (int i = 0; i < 64; ++i)
    acc = fmaf(__shfl(hv, i, 64), c2w[i * 64 + lane], acc);
  float ss = wave_sum64(xv * xv);
  xv = xv / (sqrtf(ss) + 1e-6f);
  float y = xv + acc;
  float g = gelu_tanh(y);
  float mu = wave_sum64(g) * (1.0f / 64.0f);
  float d = g - mu;
  float var = wave_sum64(d * d) * (1.0f / 64.0f);
  out[base] = d * rsqrtf(var + 1e-6f) * lns[lane] + lnb[lane];
}

// ---------------- host launcher ----------------
extern "C" void kernel_launch(void* const* d_in, const int* in_sizes, int n_in,
                              void* d_out, int out_size, void* d_ws, size_t ws_size,
                              hipStream_t stream) {
  const float* x = (const float*)d_in[0];
  const float* temb = (const float*)d_in[1];
  const float* scw = (const float*)d_in[2];
  const float* scb = (const float*)d_in[3];
  const float* swr = (const float*)d_in[4];
  const float* swi = (const float*)d_in[5];
  const float* strw = (const float*)d_in[6];
  const float* strb = (const float*)d_in[7];
  const float* stiw = (const float*)d_in[8];
  const float* stib = (const float*)d_in[9];
  const float* c1w = (const float*)d_in[10];
  const float* c1b = (const float*)d_in[11];
  const float* stw = (const float*)d_in[12];
  const float* stb = (const float*)d_in[13];
  const float* sweight = (const float*)d_in[14];
  const float* c2w = (const float*)d_in[15];
  const float* c2b = (const float*)d_in[16];
  const float* lns = (const float*)d_in[17];
  const float* lnb = (const float*)d_in[18];
  float* out = (float*)d_out;

  char* base = (char*)d_ws;
  size_t off = 0;
  auto alloc = [&](size_t bytes) -> void* {
    void* p = base + off;
    off += (bytes + 255) & ~(size_t)255;
    return p;
  };
  float* tv = (float*)alloc(128 * sizeof(float));
  float* Mm = (float*)alloc(4096 * sizeof(float));
  float* bias2 = (float*)alloc(64 * sizeof(float));
  float2* A2 = (float2*)alloc(262144 * sizeof(float2));
  float* Deff = (float*)alloc(1040384 * sizeof(float));   // [t<128][mm][l]
  float* Dinv = (float*)alloc(520192 * sizeof(float));    // [mm][l][t<64]
  float* ftmA_re = (float*)alloc(1040384 * sizeof(float));
  float* ftmA_im = (float*)alloc(1040384 * sizeof(float));
  float* ftmB_re = (float*)alloc(1040384 * sizeof(float));
  float* ftmB_im = (float*)alloc(1040384 * sizeof(float));
  float* flmA_re = (float*)alloc(520192 * sizeof(float));
  float* flmA_im = (float*)alloc(520192 * sizeof(float));
  float* flmB_re = (float*)alloc(520192 * sizeof(float));
  float* flmB_im = (float*)alloc(520192 * sizeof(float));
  if (off > ws_size) return;  // workspace too small -> visible failure
  // aliases with stage-disjoint lifetimes:
  float* s_re = ftmA_re;          // mix outputs (ftm consumed by projf)
  float* s_im = ftmA_im;
  float* h_re = ftmB_re;
  float* h_im = ftmB_im;
  float* fos_re = Deff;           // proji outputs (Deff consumed by projf/mix)
  float* fos_im = Deff + 520192;
  float* foh_re = flmA_re;        // (flmA consumed by mix)
  float* foh_im = flmA_im;
  float* xsbA = flmB_re;          // idft outputs (flmB consumed by mix)
  float* xsbB = flmB_im;
  float* hsbA = ftmA_re;          // (s consumed by proji)
  float* hsbB = ftmA_im;

  hipLaunchKernelGGL(ct_pre, dim3(896), dim3(256), 0, stream,
                     x, temb, strw, strb, stiw, stib, stw, stb,
                     scw, swr, swi, c1w, c1b, sweight,
                     Deff, Dinv, A2, Mm, bias2, tv,
                     ftmA_re, ftmA_im, ftmB_re, ftmB_im);
  hipLaunchKernelGGL(ct_projf, dim3(127, 2, 2), dim3(256), 0, stream, Deff,
                     ftmA_re, ftmA_im, ftmB_re, ftmB_im,
                     flmA_re, flmA_im, flmB_re, flmB_im);
  hipLaunchKernelGGL(ct_mix, dim3(64, 2, 2), dim3(256), 0, stream,
                     flmA_re, flmA_im, flmB_re, flmB_im, A2, Mm, scb, bias2, Deff,
                     s_re, s_im, h_re, h_im);
  hipLaunchKernelGGL(ct_proji, dim3(127, 2, 2), dim3(256), 0, stream, Dinv,
                     s_re, s_im, h_re, h_im, fos_re, fos_im, foh_re, foh_im);
  hipLaunchKernelGGL(ct_idft, dim3(64, 2, 4), dim3(256), 0, stream,
                     fos_re, fos_im, foh_re, foh_im, xsbA, xsbB, hsbA, hsbB);
  hipLaunchKernelGGL(ct_fin, dim3(2032), dim3(256), 0, stream, xsbA, xsbB, hsbA, hsbB,
                     c2w, c2b, tv, lns, lnb, out);
}

// Round 11
// 196.490 us; speedup vs baseline: 2.7720x; 1.0326x over previous
//
#include <hip/hip_runtime.h>
#include <math.h>

#define DPI 3.141592653589793238462643383279502884

// ---------------- device helpers ----------------
__device__ __forceinline__ float wave_sum64(float v) {
#pragma unroll
  for (int off = 32; off > 0; off >>= 1) v += __shfl_xor(v, off, 64);
  return v;
}

__device__ __forceinline__ float gelu_tanh(float v) {
  float u = 0.7978845608028654f * (v + 0.044715f * v * v * v);
  return 0.5f * v * (1.0f + tanhf(u));
}

#define CN255F ((float)(-2.0 * DPI / 255.0))
#define CN127F ((float)(2.0 * DPI / 127.0))

// ======================= ct_pre: dft GEMM + all setup, one launch =======================
// blocks 0..511   : forward DFT tiles (t=vb>>2, mh=(vb>>1)&1, ph=vb&1) — register twiddles
// blocks 512..766 : Wigner tables
// blocks 767..830 : A2;  831..894 : Mm/bias2;  895 : tv

__device__ __forceinline__ void dft_block(int idx, int tid, const float* __restrict__ x,
                                          float* __restrict__ Are, float* __restrict__ Aim,
                                          float* __restrict__ Bre, float* __restrict__ Bim,
                                          char* sm) {
  float* xs_ = (float*)sm;  // [64][64] 16 KB (only LDS use)
  int t = idx >> 2, mh = (idx >> 1) & 1, ph = idx & 1;
  float* ore = ph ? Bre : Are;
  float* oim = ph ? Bim : Aim;
  int pbase = ph * 128;
  int Ktot = ph ? 127 : 128;
  int cg_ = tid & 15, mg = tid >> 4;
  // register twiddles: w_j(p) = exp(i*CN255F*m_j*p), advanced by rotation per k
  float wr[4], wi[4], rc[4], rs[4];
#pragma unroll
  for (int j = 0; j < 4; ++j) {
    int gmm = mh * 64 + mg * 4 + j; if (gmm > 126) gmm = 126;
    int m = gmm - 63;
    __sincosf(CN255F * (float)m, &rs[j], &rc[j]);
    int r0 = (m * pbase) % 255;  // exact angle class; |arg| < 2*pi
    __sincosf(CN255F * (float)r0, &wi[j], &wr[j]);
  }
  float accr[4][4], acci[4][4];
#pragma unroll
  for (int j = 0; j < 4; ++j)
#pragma unroll
    for (int q = 0; q < 4; ++q) { accr[j][q] = 0.f; acci[j][q] = 0.f; }
  for (int k0 = 0; k0 < Ktot; k0 += 64) {
    int kn = (Ktot - k0 < 64) ? Ktot - k0 : 64;
    __syncthreads();
    {
      int r = tid >> 2, c4 = (tid & 3) * 16;
      if (r < kn) {
        const float4* src = (const float4*)(x + ((size_t)t * 255 + pbase + k0 + r) * 64 + c4);
        float4* dst = (float4*)&xs_[r * 64 + c4];
        dst[0] = src[0]; dst[1] = src[1]; dst[2] = src[2]; dst[3] = src[3];
      }
    }
    __syncthreads();
#pragma unroll 2
    for (int k = 0; k < kn; ++k) {
      float4 xv = *(const float4*)&xs_[k * 64 + cg_ * 4];
      float xv4[4] = {xv.x, xv.y, xv.z, xv.w};
#pragma unroll
      for (int j = 0; j < 4; ++j) {
#pragma unroll
        for (int q = 0; q < 4; ++q) {
          accr[j][q] = fmaf(xv4[q], wr[j], accr[j][q]);
          acci[j][q] = fmaf(xv4[q], wi[j], acci[j][q]);
        }
        float nw = wr[j] * rc[j] - wi[j] * rs[j];
        wi[j] = fmaf(wr[j], rs[j], wi[j] * rc[j]);
        wr[j] = nw;
      }
    }
  }
#pragma unroll
  for (int j = 0; j < 4; ++j) {
    int gmm = mh * 64 + mg * 4 + j;
    if (gmm > 126) continue;
    size_t ob = ((size_t)t * 127 + gmm) * 64 + cg_ * 4;
    *(float4*)(ore + ob) = make_float4(accr[j][0], accr[j][1], accr[j][2], accr[j][3]);
    *(float4*)(oim + ob) = make_float4(acci[j][0], acci[j][1], acci[j][2], acci[j][3]);
  }
}

__device__ __forceinline__ void wigner_block(int wb, int tid, float* __restrict__ Deff,
                                             float* __restrict__ Dinv, char* sm) {
  float* LF = (float*)sm;             // [128] log(n!)
  double* red = (double*)(sm + 512);  // [64]
  float* clf = (float*)(sm + 1024);   // [64]
  int mode = (wb < 128) ? 0 : 1;
  int t, mm;
  if (mode == 0) { t = wb; mm = tid; }
  else { mm = wb - 128; t = (tid < 64) ? tid : 63; }
  if (tid < 64) clf[tid] = (float)(-sqrt((2.0 * tid + 1.0) / (4.0 * DPI)));
  if (tid < 128) LF[tid] = (tid == 0) ? 0.f : logf((float)tid);
  __syncthreads();
  for (int s = 1; s < 128; s <<= 1) {
    float add = (tid < 128 && tid >= s) ? LF[tid - s] : 0.f;
    __syncthreads();
    if (tid < 128) LF[tid] += add;
    __syncthreads();
  }
  double denomN = (mode == 0) ? 255.0 : 127.0;
  double beta = (2.0 * t + 1.0) * DPI / denomN;
  float coeff = 1.0f;
  if (mode == 0) {
    if (tid < 63) {
      int k = 2 * (tid + 1);
      red[tid] = 8.0 * cos((double)k * beta) / (1.0 - (double)k * (double)k);
    } else if (tid == 63) {
      red[63] = 4.0;
    }
    __syncthreads();
    for (int s = 32; s > 0; s >>= 1) {
      if (tid < s) red[tid] += red[tid + s];
      __syncthreads();
    }
    double s = red[0] / 255.0;
    if (t == 127) s *= 0.5;
    coeff = (float)(s * (2.0 * DPI / 255.0));
  }
  bool active = (mode == 0) ? (tid < 127) : (tid < 64);
  if (!active) return;
  int m = mm - 63;
  double chd, shd;
  sincos(0.5 * beta, &shd, &chd);
  float cbf = (float)cos(beta);
  float chf = (float)chd, shf = (float)shd;
  int am = (m < 0) ? -m : m;
  int l0v = (am > 1) ? am : 1;
  float seed;
  if (m == 0) {
    seed = -1.4142135623730951f * shf * chf;
  } else {
    int j = am;
    float lch = logf(chf), lsh = logf(shf);
    float e0 = 0.5f * (LF[2 * j] - LF[j - 1] - LF[j + 1]);
    float expo = (m >= 1) ? e0 + (float)(j - 1) * lch + (float)(j + 1) * lsh
                          : e0 + (float)(j + 1) * lch + (float)(j - 1) * lsh;
    float sv = __expf(expo);
    seed = (m >= 1 && ((m + 1) & 1)) ? -sv : sv;
  }
  float dl = seed, dm1 = 0.0f, S_cur = 0.0f;
  float mf = (float)m;
  for (int l = 0; l < 64; ++l) {
    float val = 0.0f;
    if (l >= l0v) {
      val = dl * coeff * clf[l];
      float Ld = (float)l, lp = Ld + 1.0f;
      float S_next = sqrtf((lp * lp - mf * mf) * (lp * lp - 1.0f));
      float num1 = (2.0f * Ld + 1.0f) * (Ld * lp * cbf + mf);
      float dn = (num1 * dl - lp * S_cur * dm1) / (Ld * S_next);
      dm1 = dl; dl = dn; S_cur = S_next;
    }
    if (mode == 0) Deff[((size_t)t * 127 + mm) * 64 + l] = val;
    else Dinv[((size_t)mm * 64 + l) * 64 + t] = val;
  }
}

__device__ __forceinline__ void a2_block(int l, int tid, const float* __restrict__ temb,
                                         const float* __restrict__ trw, const float* __restrict__ trb,
                                         const float* __restrict__ tiw, const float* __restrict__ tib,
                                         const float* __restrict__ scw, const float* __restrict__ swr,
                                         const float* __restrict__ swi, float2* __restrict__ A2,
                                         char* sm) {
  float* fb1 = (float*)sm;
  float* fb2 = (float*)(sm + 1024);
  fb1[tid] = temb[tid] * trw[tid * 64 + l];
  fb2[tid] = temb[tid] * tiw[tid * 64 + l];
  __syncthreads();
  for (int s = 128; s > 0; s >>= 1) {
    if (tid < s) { fb1[tid] += fb1[tid + s]; fb2[tid] += fb2[tid + s]; }
    __syncthreads();
  }
  float tr = fb1[0] + trb[l], ti = fb2[0] + tib[l];
  int o = tid & 63, iq = tid >> 6;
  for (int i = iq * 16; i < iq * 16 + 16; ++i) {
    int idx = (l * 64 + i) * 64 + o;
    float r = swr[idx], s2 = swi[idx];
    A2[idx] = make_float2(scw[i * 64 + o] + tr * r - ti * s2, tr * s2 + ti * r);
  }
}

__device__ __forceinline__ void m_block(int j, int tid, const float* __restrict__ temb,
                                        const float* __restrict__ stw, const float* __restrict__ stb,
                                        const float* __restrict__ c1w, const float* __restrict__ c1b,
                                        const float* __restrict__ sweight, float* __restrict__ Mm,
                                        float* __restrict__ bias2, char* sm) {
  float* fb1 = (float*)sm;
  float* fb2 = (float*)(sm + 1024);
  int o = tid & 63, part = tid >> 6;
  float p = 0.f;
  for (int k = part * 64; k < part * 64 + 64; ++k)
    p = fmaf(temb[k], stw[k * 128 + o], p);
  fb1[part * 64 + o] = p;
  __syncthreads();
  if (part == 0) fb2[o] = fb1[o] + fb1[64 + o] + fb1[128 + o] + fb1[192 + o] + stb[o];
  __syncthreads();
  float tvo = fb2[o];
  float q = 0.f;
  for (int i = part * 16; i < part * 16 + 16; ++i)
    q = fmaf(c1w[j * 64 + i], sweight[i * 64 + o], q);
  __syncthreads();
  fb1[part * 64 + o] = q;
  __syncthreads();
  if (part == 0) Mm[j * 64 + o] = tvo * (fb1[o] + fb1[64 + o] + fb1[128 + o] + fb1[192 + o]);
  if (j == 0) {
    float bq = 0.f;
    for (int i = part * 16; i < part * 16 + 16; ++i)
      bq = fmaf(c1b[i], sweight[i * 64 + o], bq);
    __syncthreads();
    fb1[part * 64 + o] = bq;
    __syncthreads();
    if (part == 0) bias2[o] = tvo * (fb1[o] + fb1[64 + o] + fb1[128 + o] + fb1[192 + o]);
  }
}

__device__ __forceinline__ void tv_block(int tid, const float* __restrict__ temb,
                                         const float* __restrict__ stw, const float* __restrict__ stb,
                                         float* __restrict__ tv, char* sm) {
  float* fb1 = (float*)sm;
  int o = tid & 127, part = tid >> 7;
  float p = 0.f;
  for (int k = part * 128; k < part * 128 + 128; ++k)
    p = fmaf(temb[k], stw[k * 128 + o], p);
  fb1[part * 128 + o] = p;
  __syncthreads();
  if (part == 0) tv[o] = fb1[o] + fb1[128 + o] + stb[o];
}

__global__ __launch_bounds__(256) void ct_pre(
    const float* __restrict__ x, const float* __restrict__ temb,
    const float* __restrict__ trw, const float* __restrict__ trb,
    const float* __restrict__ tiw, const float* __restrict__ tib,
    const float* __restrict__ stw, const float* __restrict__ stb,
    const float* __restrict__ scw, const float* __restrict__ swr,
    const float* __restrict__ swi, const float* __restrict__ c1w,
    const float* __restrict__ c1b, const float* __restrict__ sweight,
    float* __restrict__ Deff, float* __restrict__ Dinv,
    float2* __restrict__ A2, float* __restrict__ Mm,
    float* __restrict__ bias2, float* __restrict__ tv,
    float* __restrict__ ftmA_re, float* __restrict__ ftmA_im,
    float* __restrict__ ftmB_re, float* __restrict__ ftmB_im) {
  __shared__ __align__(16) char sm[16384];
  int vb = blockIdx.x;
  int tid = threadIdx.x;
  if (vb < 512) dft_block(vb, tid, x, ftmA_re, ftmA_im, ftmB_re, ftmB_im, sm);
  else if (vb < 767) wigner_block(vb - 512, tid, Deff, Dinv, sm);
  else if (vb < 831) a2_block(vb - 767, tid, temb, trw, trb, tiw, tib, scw, swr, swi, A2, sm);
  else if (vb < 895) m_block(vb - 831, tid, temb, stw, stb, c1w, c1b, sweight, Mm, bias2, sm);
  else tv_block(tid, temb, stw, stb, tv, sm);
}

// ---------------- forward projection, planar, t-split over th ----------------
// grid (mm=127, lh=2, th=2), block 256.
__global__ __launch_bounds__(256) void ct_projf(const float* __restrict__ Deff,
                                                const float* __restrict__ fAre,
                                                const float* __restrict__ fAim,
                                                const float* __restrict__ fBre,
                                                const float* __restrict__ fBim,
                                                float* __restrict__ flmA_re, float* __restrict__ flmA_im,
                                                float* __restrict__ flmB_re, float* __restrict__ flmB_im) {
  __shared__ float Dsh[64][32];
  __shared__ float fr_[64][64], fi_[64][64];
  int mm = blockIdx.x, lh = blockIdx.y, th = blockIdx.z;
  float* ore = th ? flmB_re : flmA_re;
  float* oim = th ? flmB_im : flmA_im;
  int tb = th * 64;
  int tid = threadIdx.x;
  int cg_ = tid & 15, lg = tid >> 4;
  for (int e = tid; e < 64 * 32; e += 256) {
    int r = e >> 5, li = e & 31;
    Dsh[r][li] = Deff[((size_t)(tb + r) * 127 + mm) * 64 + lh * 32 + li];
  }
  for (int e = tid; e < 64 * 64; e += 256) {
    int r = e >> 6, c = e & 63;
    size_t idx = ((size_t)(tb + r) * 127 + mm) * 64 + c;
    fr_[r][c] = fAre[idx] + fBre[idx];
    fi_[r][c] = fAim[idx] + fBim[idx];
  }
  __syncthreads();
  float ar[2][4], ai[2][4];
#pragma unroll
  for (int li = 0; li < 2; ++li)
#pragma unroll
    for (int q = 0; q < 4; ++q) { ar[li][q] = 0.f; ai[li][q] = 0.f; }
#pragma unroll 4
  for (int k = 0; k < 64; ++k) {
    float4 fr4 = *(const float4*)&fr_[k][cg_ * 4];
    float4 fi4 = *(const float4*)&fi_[k][cg_ * 4];
    float2 d2 = *(const float2*)&Dsh[k][lg * 2];
    float frv[4] = {fr4.x, fr4.y, fr4.z, fr4.w};
    float fiv[4] = {fi4.x, fi4.y, fi4.z, fi4.w};
    float dv[2] = {d2.x, d2.y};
#pragma unroll
    for (int li = 0; li < 2; ++li)
#pragma unroll
      for (int q = 0; q < 4; ++q) {
        ar[li][q] = fmaf(dv[li], frv[q], ar[li][q]);
        ai[li][q] = fmaf(dv[li], fiv[q], ai[li][q]);
      }
  }
#pragma unroll
  for (int li = 0; li < 2; ++li) {
    size_t row = ((size_t)mm * 64 + lh * 32 + lg * 2 + li) * 64 + cg_ * 4;
    *(float4*)(ore + row) = make_float4(ar[li][0], ar[li][1], ar[li][2], ar[li][3]);
    *(float4*)(oim + row) = make_float4(ai[li][0], ai[li][1], ai[li][2], ai[li][3]);
  }
}

// ---------------- fused channel mixes, planar, Sl inline ----------------
// grid (l=64, mh=2, oh=2), block 256.
__global__ __launch_bounds__(256) void ct_mix(const float* __restrict__ flmA_re,
                                              const float* __restrict__ flmA_im,
                                              const float* __restrict__ flmB_re,
                                              const float* __restrict__ flmB_im,
                                              const float2* __restrict__ A2,
                                              const float* __restrict__ Mm,
                                              const float* __restrict__ scb,
                                              const float* __restrict__ bias2,
                                              const float* __restrict__ Deff,
                                              float* __restrict__ s_re, float* __restrict__ s_im,
                                              float* __restrict__ h_re, float* __restrict__ h_im) {
  __shared__ float Ar_[64][32], Ai_[64][32], Msh[64][32];
  __shared__ float Br_[64][65], Bi_[64][65];
  __shared__ float rb[256];
  int l = blockIdx.x, mh = blockIdx.y, oh = blockIdx.z;
  int tid = threadIdx.x;
  int og = tid & 15, mg = tid >> 4;
  rb[tid] = (mh == 0 && tid < 128) ? Deff[((size_t)tid * 127 + 63) * 64 + l] : 0.f;
  __syncthreads();
  for (int s = 128; s > 0; s >>= 1) {
    if (tid < s) rb[tid] += rb[tid + s];
    __syncthreads();
  }
  float slv = rb[0];
  for (int e = tid; e < 64 * 32; e += 256) {
    int r = e >> 5, oi = e & 31;
    float2 aa = A2[((size_t)l * 64 + r) * 64 + oh * 32 + oi];
    Ar_[r][oi] = aa.x; Ai_[r][oi] = aa.y;
    Msh[r][oi] = Mm[r * 64 + oh * 32 + oi];
  }
  for (int e = tid; e < 64 * 64; e += 256) {
    int mi = e >> 6, i = e & 63;
    int gmm = mh * 64 + mi; if (gmm > 126) gmm = 126;
    size_t idx = ((size_t)gmm * 64 + l) * 64 + i;
    Br_[mi][i] = flmA_re[idx] + flmB_re[idx];
    Bi_[mi][i] = flmA_im[idx] + flmB_im[idx];
  }
  __syncthreads();
  int o0 = oh * 32 + og * 2;
  float b0[2] = {scb[o0], scb[o0 + 1]};
  float sr[4][2], si[4][2], hr[4][2], hi[4][2];
#pragma unroll
  for (int jm = 0; jm < 4; ++jm)
#pragma unroll
    for (int qo = 0; qo < 2; ++qo) {
      sr[jm][qo] = b0[qo]; si[jm][qo] = 0.f; hr[jm][qo] = 0.f; hi[jm][qo] = 0.f;
    }
#pragma unroll 4
  for (int k = 0; k < 64; ++k) {
    float2 ar2 = *(const float2*)&Ar_[k][og * 2];
    float2 ai2 = *(const float2*)&Ai_[k][og * 2];
    float2 mv2 = *(const float2*)&Msh[k][og * 2];
    float br4[4], bi4[4];
#pragma unroll
    for (int jm = 0; jm < 4; ++jm) {
      br4[jm] = Br_[mg * 4 + jm][k];
      bi4[jm] = Bi_[mg * 4 + jm][k];
    }
    float arv[2] = {ar2.x, ar2.y}, aiv[2] = {ai2.x, ai2.y}, mvv[2] = {mv2.x, mv2.y};
#pragma unroll
    for (int jm = 0; jm < 4; ++jm)
#pragma unroll
      for (int qo = 0; qo < 2; ++qo) {
        sr[jm][qo] = fmaf(br4[jm], arv[qo], sr[jm][qo]);
        sr[jm][qo] = fmaf(-bi4[jm], aiv[qo], sr[jm][qo]);
        si[jm][qo] = fmaf(br4[jm], aiv[qo], si[jm][qo]);
        si[jm][qo] = fmaf(bi4[jm], arv[qo], si[jm][qo]);
        hr[jm][qo] = fmaf(br4[jm], mvv[qo], hr[jm][qo]);
        hi[jm][qo] = fmaf(bi4[jm], mvv[qo], hi[jm][qo]);
      }
  }
  float bb[2] = {bias2[o0], bias2[o0 + 1]};
#pragma unroll
  for (int jm = 0; jm < 4; ++jm) {
    int gmm = mh * 64 + mg * 4 + jm;
    if (gmm > 126) continue;
    if (gmm == 63) {
#pragma unroll
      for (int qo = 0; qo < 2; ++qo)
        hr[jm][qo] = fmaf(255.0f * slv, bb[qo], hr[jm][qo]);
    }
    size_t row = ((size_t)gmm * 64 + l) * 64 + o0;
    *(float2*)(s_re + row) = make_float2(sr[jm][0], sr[jm][1]);
    *(float2*)(s_im + row) = make_float2(si[jm][0], si[jm][1]);
    *(float2*)(h_re + row) = make_float2(hr[jm][0], hr[jm][1]);
    *(float2*)(h_im + row) = make_float2(hi[jm][0], hi[jm][1]);
  }
}

// ---------------- inverse projection, planar, c-split ----------------
// grid (mm=127, br=2, ch=2), block 256.
__global__ __launch_bounds__(256) void ct_proji(const float* __restrict__ Dinv,
                                                const float* __restrict__ s_re,
                                                const float* __restrict__ s_im,
                                                const float* __restrict__ h_re,
                                                const float* __restrict__ h_im,
                                                float* __restrict__ fos_re, float* __restrict__ fos_im,
                                                float* __restrict__ foh_re, float* __restrict__ foh_im) {
  __shared__ float Dsh[64][64];
  __shared__ float Br_[64][32], Bi_[64][32];
  int mm = blockIdx.x, br = blockIdx.y, ch = blockIdx.z;
  const float* ire = br ? h_re : s_re;
  const float* iim = br ? h_im : s_im;
  float* ore = br ? foh_re : fos_re;
  float* oim = br ? foh_im : fos_im;
  int tid = threadIdx.x;
  int cg_ = tid & 15, tg = tid >> 4;
  for (int e = tid; e < 64 * 64; e += 256) {
    int r = e >> 6, tt = e & 63;
    Dsh[r][tt] = Dinv[((size_t)mm * 64 + r) * 64 + tt];
  }
  for (int e = tid; e < 64 * 32; e += 256) {
    int r = e >> 5, cc = e & 31;
    size_t idx = ((size_t)mm * 64 + r) * 64 + ch * 32 + cc;
    Br_[r][cc] = ire[idx];
    Bi_[r][cc] = iim[idx];
  }
  __syncthreads();
  float ar[4][2], ai[4][2];
#pragma unroll
  for (int j = 0; j < 4; ++j)
#pragma unroll
    for (int q = 0; q < 2; ++q) { ar[j][q] = 0.f; ai[j][q] = 0.f; }
#pragma unroll 4
  for (int k = 0; k < 64; ++k) {
    float4 d4 = *(const float4*)&Dsh[k][tg * 4];
    float2 fr2 = *(const float2*)&Br_[k][cg_ * 2];
    float2 fi2 = *(const float2*)&Bi_[k][cg_ * 2];
    float dv[4] = {d4.x, d4.y, d4.z, d4.w};
    float frv[2] = {fr2.x, fr2.y}, fiv[2] = {fi2.x, fi2.y};
#pragma unroll
    for (int j = 0; j < 4; ++j)
#pragma unroll
      for (int q = 0; q < 2; ++q) {
        ar[j][q] = fmaf(dv[j], frv[q], ar[j][q]);
        ai[j][q] = fmaf(dv[j], fiv[q], ai[j][q]);
      }
  }
#pragma unroll
  for (int j = 0; j < 4; ++j) {
    int t = tg * 4 + j;
    size_t ob = ((size_t)t * 127 + mm) * 64 + ch * 32 + cg_ * 2;
    *(float2*)(ore + ob) = make_float2(ar[j][0], ar[j][1]);
    *(float2*)(oim + ob) = make_float2(ai[j][0], ai[j][1]);
  }
}

// ---------------- inverse DFT: tiled GEMM, register twiddles, K(mm)-split ----------------
// grid (t=64, br=2, z=4: ph=z>>1, kh=z&1), block 256. Partial sums -> {x,h}sb{A,B}.
__global__ __launch_bounds__(256) void ct_idft(const float* __restrict__ fos_re,
                                               const float* __restrict__ fos_im,
                                               const float* __restrict__ foh_re,
                                               const float* __restrict__ foh_im,
                                               float* __restrict__ xsbA, float* __restrict__ xsbB,
                                               float* __restrict__ hsbA, float* __restrict__ hsbB) {
  __shared__ float Br_[32][64], Bi_[32][64];  // 16 KB
  int t = blockIdx.x, br = blockIdx.y;
  int z = blockIdx.z;
  int ph = z >> 1, kh = z & 1;
  const float* fre = br ? foh_re : fos_re;
  const float* fim = br ? foh_im : fos_im;
  float* outp = br ? (kh ? hsbB : hsbA) : (kh ? xsbB : xsbA);
  int kbase = kh * 64;
  int Ktot = kh ? 63 : 64;
  int tid = threadIdx.x;
  int cg_ = tid & 15, pg = tid >> 4;
  // register twiddles: w_j(gmm) = exp(i*CN127F*(gmm-63)*gp_j), advanced per k
  float wc[4], ws[4], rc[4], rs[4];
#pragma unroll
  for (int j = 0; j < 4; ++j) {
    int gp = ph * 64 + pg * 4 + j; if (gp > 126) gp = 126;
    __sincosf(CN127F * (float)gp, &rs[j], &rc[j]);
    int r0 = ((kbase - 63) * gp) % 127;  // exact angle class
    __sincosf(CN127F * (float)r0, &ws[j], &wc[j]);
  }
  float acc[4][4];
#pragma unroll
  for (int j = 0; j < 4; ++j)
#pragma unroll
    for (int q = 0; q < 4; ++q) acc[j][q] = 0.f;
  for (int k0 = 0; k0 < Ktot; k0 += 32) {
    int kn = (Ktot - k0 < 32) ? Ktot - k0 : 32;
    __syncthreads();
    for (int e = tid; e < 32 * 64; e += 256) {
      int r = e >> 6, j = e & 63;
      if (r < kn) {
        size_t bidx = ((size_t)t * 127 + kbase + k0 + r) * 64 + j;
        Br_[r][j] = fre[bidx]; Bi_[r][j] = fim[bidx];
      }
    }
    __syncthreads();
#pragma unroll 2
    for (int k = 0; k < kn; ++k) {
      float4 b_r = *(const float4*)&Br_[k][cg_ * 4];
      float4 b_i = *(const float4*)&Bi_[k][cg_ * 4];
      float brv[4] = {b_r.x, b_r.y, b_r.z, b_r.w};
      float biv[4] = {b_i.x, b_i.y, b_i.z, b_i.w};
#pragma unroll
      for (int j = 0; j < 4; ++j) {
#pragma unroll
        for (int q = 0; q < 4; ++q) {
          acc[j][q] = fmaf(brv[q], wc[j], acc[j][q]);
          acc[j][q] = fmaf(biv[q], -ws[j], acc[j][q]);
        }
        float nw = wc[j] * rc[j] - ws[j] * rs[j];
        ws[j] = fmaf(wc[j], rs[j], ws[j] * rc[j]);
        wc[j] = nw;
      }
    }
  }
#pragma unroll
  for (int j = 0; j < 4; ++j) {
    int gp = ph * 64 + pg * 4 + j;
    if (gp > 126) continue;
    *(float4*)(outp + ((size_t)t * 127 + gp) * 64 + cg_ * 4) =
        make_float4(acc[j][0], acc[j][1], acc[j][2], acc[j][3]);
  }
}

// ---------------- epilogue: one wave per row ----------------
// grid 2032, block 256 (4 waves).
__global__ __launch_bounds__(256) void ct_fin(const float* __restrict__ xsbA,
                                              const float* __restrict__ xsbB,
                                              const float* __restrict__ hsbA,
                                              const float* __restrict__ hsbB,
                                              const float* __restrict__ c2w,
                                              const float* __restrict__ c2b,
                                              const float* __restrict__ tv,
                                              const float* __restrict__ lns,
                                              const float* __restrict__ lnb,
                                              float* __restrict__ out) {
  int w = threadIdx.x >> 6, lane = threadIdx.x & 63;
  size_t row = (size_t)blockIdx.x * 4 + w;  // < 8128
  size_t base = row * 64 + lane;
  float hv = hsbA[base] + hsbB[base];
  float xv = xsbA[base] + xsbB[base];
  float acc = c2b[lane] + tv[64 + lane];
#pragma unroll 16
  for (int i = 0; i < 64; ++i)
    acc = fmaf(__shfl(hv, i, 64), c2w[i * 64 + lane], acc);
  float ss = wave_sum64(xv * xv);
  xv = xv / (sqrtf(ss) + 1e-6f);
  float y = xv + acc;
  float g = gelu_tanh(y);
  float mu = wave_sum64(g) * (1.0f / 64.0f);
  float d = g - mu;
  float var = wave_sum64(d * d) * (1.0f / 64.0f);
  out[base] = d * rsqrtf(var + 1e-6f) * lns[lane] + lnb[lane];
}

// ---------------- host launcher ----------------
extern "C" void kernel_launch(void* const* d_in, const int* in_sizes, int n_in,
                              void* d_out, int out_size, void* d_ws, size_t ws_size,
                              hipStream_t stream) {
  const float* x = (const float*)d_in[0];
  const float* temb = (const float*)d_in[1];
  const float* scw = (const float*)d_in[2];
  const float* scb = (const float*)d_in[3];
  const float* swr = (const float*)d_in[4];
  const float* swi = (const float*)d_in[5];
  const float* strw = (const float*)d_in[6];
  const float* strb = (const float*)d_in[7];
  const float* stiw = (const float*)d_in[8];
  const float* stib = (const float*)d_in[9];
  const float* c1w = (const float*)d_in[10];
  const float* c1b = (const float*)d_in[11];
  const float* stw = (const float*)d_in[12];
  const float* stb = (const float*)d_in[13];
  const float* sweight = (const float*)d_in[14];
  const float* c2w = (const float*)d_in[15];
  const float* c2b = (const float*)d_in[16];
  const float* lns = (const float*)d_in[17];
  const float* lnb = (const float*)d_in[18];
  float* out = (float*)d_out;

  char* base = (char*)d_ws;
  size_t off = 0;
  auto alloc = [&](size_t bytes) -> void* {
    void* p = base + off;
    off += (bytes + 255) & ~(size_t)255;
    return p;
  };
  float* tv = (float*)alloc(128 * sizeof(float));
  float* Mm = (float*)alloc(4096 * sizeof(float));
  float* bias2 = (float*)alloc(64 * sizeof(float));
  float2* A2 = (float2*)alloc(262144 * sizeof(float2));
  float* Deff = (float*)alloc(1040384 * sizeof(float));   // [t<128][mm][l]
  float* Dinv = (float*)alloc(520192 * sizeof(float));    // [mm][l][t<64]
  float* ftmA_re = (float*)alloc(1040384 * sizeof(float));
  float* ftmA_im = (float*)alloc(1040384 * sizeof(float));
  float* ftmB_re = (float*)alloc(1040384 * sizeof(float));
  float* ftmB_im = (float*)alloc(1040384 * sizeof(float));
  float* flmA_re = (float*)alloc(520192 * sizeof(float));
  float* flmA_im = (float*)alloc(520192 * sizeof(float));
  float* flmB_re = (float*)alloc(520192 * sizeof(float));
  float* flmB_im = (float*)alloc(520192 * sizeof(float));
  if (off > ws_size) return;  // workspace too small -> visible failure
  // aliases with stage-disjoint lifetimes:
  float* s_re = ftmA_re;          // mix outputs (ftm consumed by projf)
  float* s_im = ftmA_im;
  float* h_re = ftmB_re;
  float* h_im = ftmB_im;
  float* fos_re = Deff;           // proji outputs (Deff consumed by projf/mix)
  float* fos_im = Deff + 520192;
  float* foh_re = flmA_re;        // (flmA consumed by mix)
  float* foh_im = flmA_im;
  float* xsbA = flmB_re;          // idft outputs (flmB consumed by mix)
  float* xsbB = flmB_im;
  float* hsbA = ftmA_re;          // (s consumed by proji)
  float* hsbB = ftmA_im;

  hipLaunchKernelGGL(ct_pre, dim3(896), dim3(256), 0, stream,
                     x, temb, strw, strb, stiw, stib, stw, stb,
                     scw, swr, swi, c1w, c1b, sweight,
                     Deff, Dinv, A2, Mm, bias2, tv,
                     ftmA_re, ftmA_im, ftmB_re, ftmB_im);
  hipLaunchKernelGGL(ct_projf, dim3(127, 2, 2), dim3(256), 0, stream, Deff,
                     ftmA_re, ftmA_im, ftmB_re, ftmB_im,
                     flmA_re, flmA_im, flmB_re, flmB_im);
  hipLaunchKernelGGL(ct_mix, dim3(64, 2, 2), dim3(256), 0, stream,
                     flmA_re, flmA_im, flmB_re, flmB_im, A2, Mm, scb, bias2, Deff,
                     s_re, s_im, h_re, h_im);
  hipLaunchKernelGGL(ct_proji, dim3(127, 2, 2), dim3(256), 0, stream, Dinv,
                     s_re, s_im, h_re, h_im, fos_re, fos_im, foh_re, foh_im);
  hipLaunchKernelGGL(ct_idft, dim3(64, 2, 4), dim3(256), 0, stream,
                     fos_re, fos_im, foh_re, foh_im, xsbA, xsbB, hsbA, hsbB);
  hipLaunchKernelGGL(ct_fin, dim3(2032), dim3(256), 0, stream, xsbA, xsbB, hsbA, hsbB,
                     c2w, c2b, tv, lns, lnb, out);
}

// Round 12
// 193.776 us; speedup vs baseline: 2.8109x; 1.0140x over previous
//
#include <hip/hip_runtime.h>
#include <math.h>

#define DPI 3.141592653589793238462643383279502884

// ---------------- device helpers ----------------
__device__ __forceinline__ float wave_sum64(float v) {
#pragma unroll
  for (int off = 32; off > 0; off >>= 1) v += __shfl_xor(v, off, 64);
  return v;
}

__device__ __forceinline__ float gelu_tanh(float v) {
  float u = 0.7978845608028654f * (v + 0.044715f * v * v * v);
  return 0.5f * v * (1.0f + tanhf(u));
}

#define CN255F ((float)(-2.0 * DPI / 255.0))
#define CN127F ((float)(2.0 * DPI / 127.0))

// ======================= ct_pre: setup + half-spectrum dft, one launch =======================
// blocks 0..254   : Wigner tables
// blocks 255..318 : A2;  319..382 : Mm/bias2;  383 : tv
// blocks 384..639 : forward DFT tiles (t=(vb-384)>>1, ph=(vb-384)&1), m = 0..63 ONLY
//                   (x real => ftm(-m) = conj(ftm(m)); negative half materialized in projf)
// ftm layout: [t][mi][c], mi = m = mm-63 in [0,64)

__device__ __forceinline__ void dft_block(int idx, int tid, const float* __restrict__ x,
                                          float* __restrict__ Are, float* __restrict__ Aim,
                                          float* __restrict__ Bre, float* __restrict__ Bim,
                                          char* sm) {
  float* xs_ = (float*)sm;  // [64][64] 16 KB
  int t = idx >> 1, ph = idx & 1;
  float* ore = ph ? Bre : Are;
  float* oim = ph ? Bim : Aim;
  int pbase = ph * 128;
  int Ktot = ph ? 127 : 128;
  int cg_ = tid & 15, mg = tid >> 4;
  // register twiddles: w_j(p) = exp(i*CN255F*m_j*p), m_j = mg*4+j (>=0)
  float wr[4], wi[4], rc[4], rs[4];
#pragma unroll
  for (int j = 0; j < 4; ++j) {
    int m = mg * 4 + j;
    __sincosf(CN255F * (float)m, &rs[j], &rc[j]);
    int r0 = (m * pbase) % 255;
    __sincosf(CN255F * (float)r0, &wi[j], &wr[j]);
  }
  float accr[4][4], acci[4][4];
#pragma unroll
  for (int j = 0; j < 4; ++j)
#pragma unroll
    for (int q = 0; q < 4; ++q) { accr[j][q] = 0.f; acci[j][q] = 0.f; }
  for (int k0 = 0; k0 < Ktot; k0 += 64) {
    int kn = (Ktot - k0 < 64) ? Ktot - k0 : 64;
    __syncthreads();
    {
      // fully-coalesced staging: thread tid loads float4 #(tid + q*256) of the tile
      const float4* src = (const float4*)(x + ((size_t)t * 255 + pbase + k0) * 64);
      float4* dst = (float4*)xs_;
      int lim = kn * 16;
#pragma unroll
      for (int q = 0; q < 4; ++q) {
        int fidx = tid + q * 256;
        if (fidx < lim) dst[fidx] = src[fidx];
      }
    }
    __syncthreads();
#pragma unroll 2
    for (int k = 0; k < kn; ++k) {
      float4 xv = *(const float4*)&xs_[k * 64 + cg_ * 4];
      float xv4[4] = {xv.x, xv.y, xv.z, xv.w};
#pragma unroll
      for (int j = 0; j < 4; ++j) {
#pragma unroll
        for (int q = 0; q < 4; ++q) {
          accr[j][q] = fmaf(xv4[q], wr[j], accr[j][q]);
          acci[j][q] = fmaf(xv4[q], wi[j], acci[j][q]);
        }
        float nw = wr[j] * rc[j] - wi[j] * rs[j];
        wi[j] = fmaf(wr[j], rs[j], wi[j] * rc[j]);
        wr[j] = nw;
      }
    }
  }
#pragma unroll
  for (int j = 0; j < 4; ++j) {
    int mi = mg * 4 + j;
    size_t ob = ((size_t)t * 64 + mi) * 64 + cg_ * 4;
    *(float4*)(ore + ob) = make_float4(accr[j][0], accr[j][1], accr[j][2], accr[j][3]);
    *(float4*)(oim + ob) = make_float4(acci[j][0], acci[j][1], acci[j][2], acci[j][3]);
  }
}

__device__ __forceinline__ void wigner_block(int wb, int tid, float* __restrict__ Deff,
                                             float* __restrict__ Dinv, char* sm) {
  float* LF = (float*)sm;             // [128] log(n!)
  double* red = (double*)(sm + 512);  // [64]
  float* clf = (float*)(sm + 1024);   // [64]
  int mode = (wb < 128) ? 0 : 1;
  int t, mm;
  if (mode == 0) { t = wb; mm = tid; }
  else { mm = wb - 128; t = (tid < 64) ? tid : 63; }
  if (tid < 64) clf[tid] = (float)(-sqrt((2.0 * tid + 1.0) / (4.0 * DPI)));
  if (tid < 128) LF[tid] = (tid == 0) ? 0.f : logf((float)tid);
  __syncthreads();
  for (int s = 1; s < 128; s <<= 1) {
    float add = (tid < 128 && tid >= s) ? LF[tid - s] : 0.f;
    __syncthreads();
    if (tid < 128) LF[tid] += add;
    __syncthreads();
  }
  double denomN = (mode == 0) ? 255.0 : 127.0;
  double beta = (2.0 * t + 1.0) * DPI / denomN;
  float coeff = 1.0f;
  if (mode == 0) {
    if (tid < 63) {
      int k = 2 * (tid + 1);
      red[tid] = 8.0 * cos((double)k * beta) / (1.0 - (double)k * (double)k);
    } else if (tid == 63) {
      red[63] = 4.0;
    }
    __syncthreads();
    for (int s = 32; s > 0; s >>= 1) {
      if (tid < s) red[tid] += red[tid + s];
      __syncthreads();
    }
    double s = red[0] / 255.0;
    if (t == 127) s *= 0.5;
    coeff = (float)(s * (2.0 * DPI / 255.0));
  }
  bool active = (mode == 0) ? (tid < 127) : (tid < 64);
  if (!active) return;
  int m = mm - 63;
  double chd, shd;
  sincos(0.5 * beta, &shd, &chd);
  float cbf = (float)cos(beta);
  float chf = (float)chd, shf = (float)shd;
  int am = (m < 0) ? -m : m;
  int l0v = (am > 1) ? am : 1;
  float seed;
  if (m == 0) {
    seed = -1.4142135623730951f * shf * chf;
  } else {
    int j = am;
    float lch = logf(chf), lsh = logf(shf);
    float e0 = 0.5f * (LF[2 * j] - LF[j - 1] - LF[j + 1]);
    float expo = (m >= 1) ? e0 + (float)(j - 1) * lch + (float)(j + 1) * lsh
                          : e0 + (float)(j + 1) * lch + (float)(j - 1) * lsh;
    float sv = __expf(expo);
    seed = (m >= 1 && ((m + 1) & 1)) ? -sv : sv;
  }
  float dl = seed, dm1 = 0.0f, S_cur = 0.0f;
  float mf = (float)m;
  for (int l = 0; l < 64; ++l) {
    float val = 0.0f;
    if (l >= l0v) {
      val = dl * coeff * clf[l];
      float Ld = (float)l, lp = Ld + 1.0f;
      float S_next = sqrtf((lp * lp - mf * mf) * (lp * lp - 1.0f));
      float num1 = (2.0f * Ld + 1.0f) * (Ld * lp * cbf + mf);
      float dn = (num1 * dl - lp * S_cur * dm1) / (Ld * S_next);
      dm1 = dl; dl = dn; S_cur = S_next;
    }
    if (mode == 0) Deff[((size_t)t * 127 + mm) * 64 + l] = val;
    else Dinv[((size_t)mm * 64 + l) * 64 + t] = val;
  }
}

__device__ __forceinline__ void a2_block(int l, int tid, const float* __restrict__ temb,
                                         const float* __restrict__ trw, const float* __restrict__ trb,
                                         const float* __restrict__ tiw, const float* __restrict__ tib,
                                         const float* __restrict__ scw, const float* __restrict__ swr,
                                         const float* __restrict__ swi, float2* __restrict__ A2,
                                         char* sm) {
  float* fb1 = (float*)sm;
  float* fb2 = (float*)(sm + 1024);
  fb1[tid] = temb[tid] * trw[tid * 64 + l];
  fb2[tid] = temb[tid] * tiw[tid * 64 + l];
  __syncthreads();
  for (int s = 128; s > 0; s >>= 1) {
    if (tid < s) { fb1[tid] += fb1[tid + s]; fb2[tid] += fb2[tid + s]; }
    __syncthreads();
  }
  float tr = fb1[0] + trb[l], ti = fb2[0] + tib[l];
  int o = tid & 63, iq = tid >> 6;
  for (int i = iq * 16; i < iq * 16 + 16; ++i) {
    int idx = (l * 64 + i) * 64 + o;
    float r = swr[idx], s2 = swi[idx];
    A2[idx] = make_float2(scw[i * 64 + o] + tr * r - ti * s2, tr * s2 + ti * r);
  }
}

__device__ __forceinline__ void m_block(int j, int tid, const float* __restrict__ temb,
                                        const float* __restrict__ stw, const float* __restrict__ stb,
                                        const float* __restrict__ c1w, const float* __restrict__ c1b,
                                        const float* __restrict__ sweight, float* __restrict__ Mm,
                                        float* __restrict__ bias2, char* sm) {
  float* fb1 = (float*)sm;
  float* fb2 = (float*)(sm + 1024);
  int o = tid & 63, part = tid >> 6;
  float p = 0.f;
  for (int k = part * 64; k < part * 64 + 64; ++k)
    p = fmaf(temb[k], stw[k * 128 + o], p);
  fb1[part * 64 + o] = p;
  __syncthreads();
  if (part == 0) fb2[o] = fb1[o] + fb1[64 + o] + fb1[128 + o] + fb1[192 + o] + stb[o];
  __syncthreads();
  float tvo = fb2[o];
  float q = 0.f;
  for (int i = part * 16; i < part * 16 + 16; ++i)
    q = fmaf(c1w[j * 64 + i], sweight[i * 64 + o], q);
  __syncthreads();
  fb1[part * 64 + o] = q;
  __syncthreads();
  if (part == 0) Mm[j * 64 + o] = tvo * (fb1[o] + fb1[64 + o] + fb1[128 + o] + fb1[192 + o]);
  if (j == 0) {
    float bq = 0.f;
    for (int i = part * 16; i < part * 16 + 16; ++i)
      bq = fmaf(c1b[i], sweight[i * 64 + o], bq);
    __syncthreads();
    fb1[part * 64 + o] = bq;
    __syncthreads();
    if (part == 0) bias2[o] = tvo * (fb1[o] + fb1[64 + o] + fb1[128 + o] + fb1[192 + o]);
  }
}

__device__ __forceinline__ void tv_block(int tid, const float* __restrict__ temb,
                                         const float* __restrict__ stw, const float* __restrict__ stb,
                                         float* __restrict__ tv, char* sm) {
  float* fb1 = (float*)sm;
  int o = tid & 127, part = tid >> 7;
  float p = 0.f;
  for (int k = part * 128; k < part * 128 + 128; ++k)
    p = fmaf(temb[k], stw[k * 128 + o], p);
  fb1[part * 128 + o] = p;
  __syncthreads();
  if (part == 0) tv[o] = fb1[o] + fb1[128 + o] + stb[o];
}

__global__ __launch_bounds__(256) void ct_pre(
    const float* __restrict__ x, const float* __restrict__ temb,
    const float* __restrict__ trw, const float* __restrict__ trb,
    const float* __restrict__ tiw, const float* __restrict__ tib,
    const float* __restrict__ stw, const float* __restrict__ stb,
    const float* __restrict__ scw, const float* __restrict__ swr,
    const float* __restrict__ swi, const float* __restrict__ c1w,
    const float* __restrict__ c1b, const float* __restrict__ sweight,
    float* __restrict__ Deff, float* __restrict__ Dinv,
    float2* __restrict__ A2, float* __restrict__ Mm,
    float* __restrict__ bias2, float* __restrict__ tv,
    float* __restrict__ ftmA_re, float* __restrict__ ftmA_im,
    float* __restrict__ ftmB_re, float* __restrict__ ftmB_im) {
  __shared__ __align__(16) char sm[16384];
  int vb = blockIdx.x;
  int tid = threadIdx.x;
  if (vb < 255) wigner_block(vb, tid, Deff, Dinv, sm);
  else if (vb < 319) a2_block(vb - 255, tid, temb, trw, trb, tiw, tib, scw, swr, swi, A2, sm);
  else if (vb < 383) m_block(vb - 319, tid, temb, stw, stb, c1w, c1b, sweight, Mm, bias2, sm);
  else if (vb < 384) tv_block(tid, temb, stw, stb, tv, sm);
  else dft_block(vb - 384, tid, x, ftmA_re, ftmA_im, ftmB_re, ftmB_im, sm);
}

// ---------------- forward projection, planar, t-split; conj-expands half-spectrum ftm ----------------
// grid (mm=127, lh=2, th=2), block 256. ftm layout [t][mi][c], mi=m>=0; mm<63 -> conj of mi=63-mm.
__global__ __launch_bounds__(256) void ct_projf(const float* __restrict__ Deff,
                                                const float* __restrict__ fAre,
                                                const float* __restrict__ fAim,
                                                const float* __restrict__ fBre,
                                                const float* __restrict__ fBim,
                                                float* __restrict__ flmA_re, float* __restrict__ flmA_im,
                                                float* __restrict__ flmB_re, float* __restrict__ flmB_im) {
  __shared__ float Dsh[64][32];
  __shared__ float fr_[64][64], fi_[64][64];
  int mm = blockIdx.x, lh = blockIdx.y, th = blockIdx.z;
  float* ore = th ? flmB_re : flmA_re;
  float* oim = th ? flmB_im : flmA_im;
  int tb = th * 64;
  int mi = (mm >= 63) ? (mm - 63) : (63 - mm);
  float csign = (mm >= 63) ? 1.0f : -1.0f;
  int tid = threadIdx.x;
  int cg_ = tid & 15, lg = tid >> 4;
  for (int e = tid; e < 64 * 32; e += 256) {
    int r = e >> 5, li = e & 31;
    Dsh[r][li] = Deff[((size_t)(tb + r) * 127 + mm) * 64 + lh * 32 + li];
  }
  for (int e = tid; e < 64 * 64; e += 256) {
    int r = e >> 6, c = e & 63;
    size_t idx = ((size_t)(tb + r) * 64 + mi) * 64 + c;
    fr_[r][c] = fAre[idx] + fBre[idx];
    fi_[r][c] = csign * (fAim[idx] + fBim[idx]);
  }
  __syncthreads();
  float ar[2][4], ai[2][4];
#pragma unroll
  for (int li = 0; li < 2; ++li)
#pragma unroll
    for (int q = 0; q < 4; ++q) { ar[li][q] = 0.f; ai[li][q] = 0.f; }
#pragma unroll 4
  for (int k = 0; k < 64; ++k) {
    float4 fr4 = *(const float4*)&fr_[k][cg_ * 4];
    float4 fi4 = *(const float4*)&fi_[k][cg_ * 4];
    float2 d2 = *(const float2*)&Dsh[k][lg * 2];
    float frv[4] = {fr4.x, fr4.y, fr4.z, fr4.w};
    float fiv[4] = {fi4.x, fi4.y, fi4.z, fi4.w};
    float dv[2] = {d2.x, d2.y};
#pragma unroll
    for (int li = 0; li < 2; ++li)
#pragma unroll
      for (int q = 0; q < 4; ++q) {
        ar[li][q] = fmaf(dv[li], frv[q], ar[li][q]);
        ai[li][q] = fmaf(dv[li], fiv[q], ai[li][q]);
      }
  }
#pragma unroll
  for (int li = 0; li < 2; ++li) {
    size_t row = ((size_t)mm * 64 + lh * 32 + lg * 2 + li) * 64 + cg_ * 4;
    *(float4*)(ore + row) = make_float4(ar[li][0], ar[li][1], ar[li][2], ar[li][3]);
    *(float4*)(oim + row) = make_float4(ai[li][0], ai[li][1], ai[li][2], ai[li][3]);
  }
}

// ---------------- fused channel mixes, planar, Sl inline ----------------
// grid (l=64, mh=2, oh=2), block 256.
__global__ __launch_bounds__(256) void ct_mix(const float* __restrict__ flmA_re,
                                              const float* __restrict__ flmA_im,
                                              const float* __restrict__ flmB_re,
                                              const float* __restrict__ flmB_im,
                                              const float2* __restrict__ A2,
                                              const float* __restrict__ Mm,
                                              const float* __restrict__ scb,
                                              const float* __restrict__ bias2,
                                              const float* __restrict__ Deff,
                                              float* __restrict__ s_re, float* __restrict__ s_im,
                                              float* __restrict__ h_re, float* __restrict__ h_im) {
  __shared__ float Ar_[64][32], Ai_[64][32], Msh[64][32];
  __shared__ float Br_[64][65], Bi_[64][65];
  __shared__ float rb[256];
  int l = blockIdx.x, mh = blockIdx.y, oh = blockIdx.z;
  int tid = threadIdx.x;
  int og = tid & 15, mg = tid >> 4;
  rb[tid] = (mh == 0 && tid < 128) ? Deff[((size_t)tid * 127 + 63) * 64 + l] : 0.f;
  __syncthreads();
  for (int s = 128; s > 0; s >>= 1) {
    if (tid < s) rb[tid] += rb[tid + s];
    __syncthreads();
  }
  float slv = rb[0];
  for (int e = tid; e < 64 * 32; e += 256) {
    int r = e >> 5, oi = e & 31;
    float2 aa = A2[((size_t)l * 64 + r) * 64 + oh * 32 + oi];
    Ar_[r][oi] = aa.x; Ai_[r][oi] = aa.y;
    Msh[r][oi] = Mm[r * 64 + oh * 32 + oi];
  }
  for (int e = tid; e < 64 * 64; e += 256) {
    int mi = e >> 6, i = e & 63;
    int gmm = mh * 64 + mi; if (gmm > 126) gmm = 126;
    size_t idx = ((size_t)gmm * 64 + l) * 64 + i;
    Br_[mi][i] = flmA_re[idx] + flmB_re[idx];
    Bi_[mi][i] = flmA_im[idx] + flmB_im[idx];
  }
  __syncthreads();
  int o0 = oh * 32 + og * 2;
  float b0[2] = {scb[o0], scb[o0 + 1]};
  float sr[4][2], si[4][2], hr[4][2], hi[4][2];
#pragma unroll
  for (int jm = 0; jm < 4; ++jm)
#pragma unroll
    for (int qo = 0; qo < 2; ++qo) {
      sr[jm][qo] = b0[qo]; si[jm][qo] = 0.f; hr[jm][qo] = 0.f; hi[jm][qo] = 0.f;
    }
#pragma unroll 4
  for (int k = 0; k < 64; ++k) {
    float2 ar2 = *(const float2*)&Ar_[k][og * 2];
    float2 ai2 = *(const float2*)&Ai_[k][og * 2];
    float2 mv2 = *(const float2*)&Msh[k][og * 2];
    float br4[4], bi4[4];
#pragma unroll
    for (int jm = 0; jm < 4; ++jm) {
      br4[jm] = Br_[mg * 4 + jm][k];
      bi4[jm] = Bi_[mg * 4 + jm][k];
    }
    float arv[2] = {ar2.x, ar2.y}, aiv[2] = {ai2.x, ai2.y}, mvv[2] = {mv2.x, mv2.y};
#pragma unroll
    for (int jm = 0; jm < 4; ++jm)
#pragma unroll
      for (int qo = 0; qo < 2; ++qo) {
        sr[jm][qo] = fmaf(br4[jm], arv[qo], sr[jm][qo]);
        sr[jm][qo] = fmaf(-bi4[jm], aiv[qo], sr[jm][qo]);
        si[jm][qo] = fmaf(br4[jm], aiv[qo], si[jm][qo]);
        si[jm][qo] = fmaf(bi4[jm], arv[qo], si[jm][qo]);
        hr[jm][qo] = fmaf(br4[jm], mvv[qo], hr[jm][qo]);
        hi[jm][qo] = fmaf(bi4[jm], mvv[qo], hi[jm][qo]);
      }
  }
  float bb[2] = {bias2[o0], bias2[o0 + 1]};
#pragma unroll
  for (int jm = 0; jm < 4; ++jm) {
    int gmm = mh * 64 + mg * 4 + jm;
    if (gmm > 126) continue;
    if (gmm == 63) {
#pragma unroll
      for (int qo = 0; qo < 2; ++qo)
        hr[jm][qo] = fmaf(255.0f * slv, bb[qo], hr[jm][qo]);
    }
    size_t row = ((size_t)gmm * 64 + l) * 64 + o0;
    *(float2*)(s_re + row) = make_float2(sr[jm][0], sr[jm][1]);
    *(float2*)(s_im + row) = make_float2(si[jm][0], si[jm][1]);
    *(float2*)(h_re + row) = make_float2(hr[jm][0], hr[jm][1]);
    *(float2*)(h_im + row) = make_float2(hi[jm][0], hi[jm][1]);
  }
}

// ---------------- inverse projection, planar, c-split ----------------
// grid (mm=127, br=2, ch=2), block 256.
__global__ __launch_bounds__(256) void ct_proji(const float* __restrict__ Dinv,
                                                const float* __restrict__ s_re,
                                                const float* __restrict__ s_im,
                                                const float* __restrict__ h_re,
                                                const float* __restrict__ h_im,
                                                float* __restrict__ fos_re, float* __restrict__ fos_im,
                                                float* __restrict__ foh_re, float* __restrict__ foh_im) {
  __shared__ float Dsh[64][64];
  __shared__ float Br_[64][32], Bi_[64][32];
  int mm = blockIdx.x, br = blockIdx.y, ch = blockIdx.z;
  const float* ire = br ? h_re : s_re;
  const float* iim = br ? h_im : s_im;
  float* ore = br ? foh_re : fos_re;
  float* oim = br ? foh_im : fos_im;
  int tid = threadIdx.x;
  int cg_ = tid & 15, tg = tid >> 4;
  for (int e = tid; e < 64 * 64; e += 256) {
    int r = e >> 6, tt = e & 63;
    Dsh[r][tt] = Dinv[((size_t)mm * 64 + r) * 64 + tt];
  }
  for (int e = tid; e < 64 * 32; e += 256) {
    int r = e >> 5, cc = e & 31;
    size_t idx = ((size_t)mm * 64 + r) * 64 + ch * 32 + cc;
    Br_[r][cc] = ire[idx];
    Bi_[r][cc] = iim[idx];
  }
  __syncthreads();
  float ar[4][2], ai[4][2];
#pragma unroll
  for (int j = 0; j < 4; ++j)
#pragma unroll
    for (int q = 0; q < 2; ++q) { ar[j][q] = 0.f; ai[j][q] = 0.f; }
#pragma unroll 4
  for (int k = 0; k < 64; ++k) {
    float4 d4 = *(const float4*)&Dsh[k][tg * 4];
    float2 fr2 = *(const float2*)&Br_[k][cg_ * 2];
    float2 fi2 = *(const float2*)&Bi_[k][cg_ * 2];
    float dv[4] = {d4.x, d4.y, d4.z, d4.w};
    float frv[2] = {fr2.x, fr2.y}, fiv[2] = {fi2.x, fi2.y};
#pragma unroll
    for (int j = 0; j < 4; ++j)
#pragma unroll
      for (int q = 0; q < 2; ++q) {
        ar[j][q] = fmaf(dv[j], frv[q], ar[j][q]);
        ai[j][q] = fmaf(dv[j], fiv[q], ai[j][q]);
      }
  }
#pragma unroll
  for (int j = 0; j < 4; ++j) {
    int t = tg * 4 + j;
    size_t ob = ((size_t)t * 127 + mm) * 64 + ch * 32 + cg_ * 2;
    *(float2*)(ore + ob) = make_float2(ar[j][0], ar[j][1]);
    *(float2*)(oim + ob) = make_float2(ai[j][0], ai[j][1]);
  }
}

// ---------------- inverse DFT: tiled GEMM, register twiddles, K(mm)-split ----------------
// grid (t=64, br=2, z=4: ph=z>>1, kh=z&1), block 256.
__global__ __launch_bounds__(256) void ct_idft(const float* __restrict__ fos_re,
                                               const float* __restrict__ fos_im,
                                               const float* __restrict__ foh_re,
                                               const float* __restrict__ foh_im,
                                               float* __restrict__ xsbA, float* __restrict__ xsbB,
                                               float* __restrict__ hsbA, float* __restrict__ hsbB) {
  __shared__ float Br_[32][64], Bi_[32][64];  // 16 KB
  int t = blockIdx.x, br = blockIdx.y;
  int z = blockIdx.z;
  int ph = z >> 1, kh = z & 1;
  const float* fre = br ? foh_re : fos_re;
  const float* fim = br ? foh_im : fos_im;
  float* outp = br ? (kh ? hsbB : hsbA) : (kh ? xsbB : xsbA);
  int kbase = kh * 64;
  int Ktot = kh ? 63 : 64;
  int tid = threadIdx.x;
  int cg_ = tid & 15, pg = tid >> 4;
  float wc[4], ws[4], rc[4], rs[4];
#pragma unroll
  for (int j = 0; j < 4; ++j) {
    int gp = ph * 64 + pg * 4 + j; if (gp > 126) gp = 126;
    __sincosf(CN127F * (float)gp, &rs[j], &rc[j]);
    int r0 = ((kbase - 63) * gp) % 127;
    __sincosf(CN127F * (float)r0, &ws[j], &wc[j]);
  }
  float acc[4][4];
#pragma unroll
  for (int j = 0; j < 4; ++j)
#pragma unroll
    for (int q = 0; q < 4; ++q) acc[j][q] = 0.f;
  for (int k0 = 0; k0 < Ktot; k0 += 32) {
    int kn = (Ktot - k0 < 32) ? Ktot - k0 : 32;
    __syncthreads();
    for (int e = tid; e < 32 * 64; e += 256) {
      int r = e >> 6, j = e & 63;
      if (r < kn) {
        size_t bidx = ((size_t)t * 127 + kbase + k0 + r) * 64 + j;
        Br_[r][j] = fre[bidx]; Bi_[r][j] = fim[bidx];
      }
    }
    __syncthreads();
#pragma unroll 2
    for (int k = 0; k < kn; ++k) {
      float4 b_r = *(const float4*)&Br_[k][cg_ * 4];
      float4 b_i = *(const float4*)&Bi_[k][cg_ * 4];
      float brv[4] = {b_r.x, b_r.y, b_r.z, b_r.w};
      float biv[4] = {b_i.x, b_i.y, b_i.z, b_i.w};
#pragma unroll
      for (int j = 0; j < 4; ++j) {
#pragma unroll
        for (int q = 0; q < 4; ++q) {
          acc[j][q] = fmaf(brv[q], wc[j], acc[j][q]);
          acc[j][q] = fmaf(biv[q], -ws[j], acc[j][q]);
        }
        float nw = wc[j] * rc[j] - ws[j] * rs[j];
        ws[j] = fmaf(wc[j], rs[j], ws[j] * rc[j]);
        wc[j] = nw;
      }
    }
  }
#pragma unroll
  for (int j = 0; j < 4; ++j) {
    int gp = ph * 64 + pg * 4 + j;
    if (gp > 126) continue;
    *(float4*)(outp + ((size_t)t * 127 + gp) * 64 + cg_ * 4) =
        make_float4(acc[j][0], acc[j][1], acc[j][2], acc[j][3]);
  }
}

// ---------------- epilogue: one wave per row ----------------
// grid 2032, block 256 (4 waves).
__global__ __launch_bounds__(256) void ct_fin(const float* __restrict__ xsbA,
                                              const float* __restrict__ xsbB,
                                              const float* __restrict__ hsbA,
                                              const float* __restrict__ hsbB,
                                              const float* __restrict__ c2w,
                                              const float* __restrict__ c2b,
                                              const float* __restrict__ tv,
                                              const float* __restrict__ lns,
                                              const float* __restrict__ lnb,
                                              float* __restrict__ out) {
  int w = threadIdx.x >> 6, lane = threadIdx.x & 63;
  size_t row = (size_t)blockIdx.x * 4 + w;  // < 8128
  size_t base = row * 64 + lane;
  float hv = hsbA[base] + hsbB[base];
  float xv = xsbA[base] + xsbB[base];
  float acc = c2b[lane] + tv[64 + lane];
#pragma unroll 16
  for (int i = 0; i < 64; ++i)
    acc = fmaf(__shfl(hv, i, 64), c2w[i * 64 + lane], acc);
  float ss = wave_sum64(xv * xv);
  xv = xv / (sqrtf(ss) + 1e-6f);
  float y = xv + acc;
  float g = gelu_tanh(y);
  float mu = wave_sum64(g) * (1.0f / 64.0f);
  float d = g - mu;
  float var = wave_sum64(d * d) * (1.0f / 64.0f);
  out[base] = d * rsqrtf(var + 1e-6f) * lns[lane] + lnb[lane];
}

// ---------------- host launcher ----------------
extern "C" void kernel_launch(void* const* d_in, const int* in_sizes, int n_in,
                              void* d_out, int out_size, void* d_ws, size_t ws_size,
                              hipStream_t stream) {
  const float* x = (const float*)d_in[0];
  const float* temb = (const float*)d_in[1];
  const float* scw = (const float*)d_in[2];
  const float* scb = (const float*)d_in[3];
  const float* swr = (const float*)d_in[4];
  const float* swi = (const float*)d_in[5];
  const float* strw = (const float*)d_in[6];
  const float* strb = (const float*)d_in[7];
  const float* stiw = (const float*)d_in[8];
  const float* stib = (const float*)d_in[9];
  const float* c1w = (const float*)d_in[10];
  const float* c1b = (const float*)d_in[11];
  const float* stw = (const float*)d_in[12];
  const float* stb = (const float*)d_in[13];
  const float* sweight = (const float*)d_in[14];
  const float* c2w = (const float*)d_in[15];
  const float* c2b = (const float*)d_in[16];
  const float* lns = (const float*)d_in[17];
  const float* lnb = (const float*)d_in[18];
  float* out = (float*)d_out;

  char* base = (char*)d_ws;
  size_t off = 0;
  auto alloc = [&](size_t bytes) -> void* {
    void* p = base + off;
    off += (bytes + 255) & ~(size_t)255;
    return p;
  };
  float* tv = (float*)alloc(128 * sizeof(float));
  float* Mm = (float*)alloc(4096 * sizeof(float));
  float* bias2 = (float*)alloc(64 * sizeof(float));
  float2* A2 = (float2*)alloc(262144 * sizeof(float2));
  float* Deff = (float*)alloc(1040384 * sizeof(float));   // [t<128][mm][l]
  float* Dinv = (float*)alloc(520192 * sizeof(float));    // [mm][l][t<64]
  float* ftmA_re = (float*)alloc(524288 * sizeof(float)); // [t<128][mi<64][c] half-spectrum
  float* ftmA_im = (float*)alloc(524288 * sizeof(float));
  float* ftmB_re = (float*)alloc(524288 * sizeof(float));
  float* ftmB_im = (float*)alloc(524288 * sizeof(float));
  float* flmA_re = (float*)alloc(520192 * sizeof(float));
  float* flmA_im = (float*)alloc(520192 * sizeof(float));
  float* flmB_re = (float*)alloc(520192 * sizeof(float));
  float* flmB_im = (float*)alloc(520192 * sizeof(float));
  if (off > ws_size) return;  // workspace too small -> visible failure
  // aliases with stage-disjoint lifetimes (each target >= 520192 floats):
  float* s_re = ftmA_re;          // mix outputs (ftm consumed by projf)
  float* s_im = ftmA_im;
  float* h_re = ftmB_re;
  float* h_im = ftmB_im;
  float* fos_re = Deff;           // proji outputs (Deff consumed by projf/mix)
  float* fos_im = Deff + 520192;
  float* foh_re = flmA_re;        // (flmA consumed by mix)
  float* foh_im = flmA_im;
  float* xsbA = flmB_re;          // idft outputs (flmB consumed by mix)
  float* xsbB = flmB_im;
  float* hsbA = ftmA_re;          // (s consumed by proji)
  float* hsbB = ftmA_im;

  hipLaunchKernelGGL(ct_pre, dim3(640), dim3(256), 0, stream,
                     x, temb, strw, strb, stiw, stib, stw, stb,
                     scw, swr, swi, c1w, c1b, sweight,
                     Deff, Dinv, A2, Mm, bias2, tv,
                     ftmA_re, ftmA_im, ftmB_re, ftmB_im);
  hipLaunchKernelGGL(ct_projf, dim3(127, 2, 2), dim3(256), 0, stream, Deff,
                     ftmA_re, ftmA_im, ftmB_re, ftmB_im,
                     flmA_re, flmA_im, flmB_re, flmB_im);
  hipLaunchKernelGGL(ct_mix, dim3(64, 2, 2), dim3(256), 0, stream,
                     flmA_re, flmA_im, flmB_re, flmB_im, A2, Mm, scb, bias2, Deff,
                     s_re, s_im, h_re, h_im);
  hipLaunchKernelGGL(ct_proji, dim3(127, 2, 2), dim3(256), 0, stream, Dinv,
                     s_re, s_im, h_re, h_im, fos_re, fos_im, foh_re, foh_im);
  hipLaunchKernelGGL(ct_idft, dim3(64, 2, 4), dim3(256), 0, stream,
                     fos_re, fos_im, foh_re, foh_im, xsbA, xsbB, hsbA, hsbB);
  hipLaunchKernelGGL(ct_fin, dim3(2032), dim3(256), 0, stream, xsbA, xsbB, hsbA, hsbB,
                     c2w, c2b, tv, lns, lnb, out);
}